// Round 2
// baseline (438.660 us; speedup 1.0000x reference)
//
#include <hip/hip_runtime.h>

typedef unsigned short u16;
typedef short bf16x8 __attribute__((ext_vector_type(8)));
typedef float f32x4 __attribute__((ext_vector_type(4)));
typedef unsigned short u16x4 __attribute__((ext_vector_type(4)));
typedef unsigned int u32x4 __attribute__((ext_vector_type(4)));

__device__ __forceinline__ u16 f2b(float f) {
    unsigned u = __float_as_uint(f);
    u += 0x7fffu + ((u >> 16) & 1u);
    return (u16)(u >> 16);
}
__device__ __forceinline__ float b2f(u16 h) { return __uint_as_float((unsigned)h << 16); }

// ---------------- transpose + cast fp32 -> bf16, Wt[n][k] = W[k][n] ----------------
__global__ void transpose_cast(const float* __restrict__ W, u16* __restrict__ Wt,
                               int K, int N) {
    __shared__ float t[32][33];
    const int n0 = blockIdx.x * 32, k0 = blockIdx.y * 32;
    const int tx = threadIdx.x, ty = threadIdx.y;
#pragma unroll
    for (int i = 0; i < 32; i += 8)
        t[ty + i][tx] = W[(size_t)(k0 + ty + i) * N + n0 + tx];
    __syncthreads();
#pragma unroll
    for (int i = 0; i < 32; i += 8)
        Wt[(size_t)(n0 + ty + i) * K + k0 + tx] = f2b(t[tx][ty + i]);
}

// ---------------- transpose + split cast fp32 -> bf16 hi/lo ----------------
__global__ void transpose_cast_split(const float* __restrict__ W, u16* __restrict__ WtH,
                                     u16* __restrict__ WtL, int K, int N) {
    __shared__ float t[32][33];
    const int n0 = blockIdx.x * 32, k0 = blockIdx.y * 32;
    const int tx = threadIdx.x, ty = threadIdx.y;
#pragma unroll
    for (int i = 0; i < 32; i += 8)
        t[ty + i][tx] = W[(size_t)(k0 + ty + i) * N + n0 + tx];
    __syncthreads();
#pragma unroll
    for (int i = 0; i < 32; i += 8) {
        const float v = t[tx][ty + i];
        const u16 hi = f2b(v);
        const size_t idx = (size_t)(n0 + ty + i) * K + k0 + tx;
        WtH[idx] = hi;
        WtL[idx] = f2b(v - b2f(hi));
    }
}

// ---------------- LayerNorm fp32 -> bf16, D=1024, one block per row ----------------
__global__ __launch_bounds__(256) void ln_f32_bf16(const float* __restrict__ in,
                                                   const float* __restrict__ g,
                                                   const float* __restrict__ b,
                                                   u16* __restrict__ out) {
    constexpr int Dl = 1024;
    const int row = blockIdx.x, tid = threadIdx.x;
    const float4 v = *(const float4*)&in[(size_t)row * Dl + tid * 4];
    const float* vp = (const float*)&v;
    float s = v.x + v.y + v.z + v.w;
    float s2 = v.x * v.x + v.y * v.y + v.z * v.z + v.w * v.w;
#pragma unroll
    for (int off = 32; off; off >>= 1) { s += __shfl_xor(s, off); s2 += __shfl_xor(s2, off); }
    __shared__ float red[8];
    const int lane = tid & 63, wid = tid >> 6;
    if (lane == 0) { red[wid] = s; red[4 + wid] = s2; }
    __syncthreads();
    s = red[0] + red[1] + red[2] + red[3];
    s2 = red[4] + red[5] + red[6] + red[7];
    const float mean = s * (1.0f / Dl);
    const float rstd = rsqrtf(s2 * (1.0f / Dl) - mean * mean + 1e-5f);
    u16x4 pk;
#pragma unroll
    for (int i = 0; i < 4; ++i) {
        const int col = tid * 4 + i;
        pk[i] = f2b((vp[i] - mean) * rstd * g[col] + b[col]);
    }
    *(u16x4*)&out[(size_t)row * Dl + tid * 4] = pk;
}

// ---------------- LayerNorm fp32 -> bf16 hi/lo pair ----------------
__global__ __launch_bounds__(256) void ln_f32_bf16_split(const float* __restrict__ in,
                                                         const float* __restrict__ g,
                                                         const float* __restrict__ b,
                                                         u16* __restrict__ outH,
                                                         u16* __restrict__ outL) {
    constexpr int Dl = 1024;
    const int row = blockIdx.x, tid = threadIdx.x;
    const float4 v = *(const float4*)&in[(size_t)row * Dl + tid * 4];
    const float* vp = (const float*)&v;
    float s = v.x + v.y + v.z + v.w;
    float s2 = v.x * v.x + v.y * v.y + v.z * v.z + v.w * v.w;
#pragma unroll
    for (int off = 32; off; off >>= 1) { s += __shfl_xor(s, off); s2 += __shfl_xor(s2, off); }
    __shared__ float red[8];
    const int lane = tid & 63, wid = tid >> 6;
    if (lane == 0) { red[wid] = s; red[4 + wid] = s2; }
    __syncthreads();
    s = red[0] + red[1] + red[2] + red[3];
    s2 = red[4] + red[5] + red[6] + red[7];
    const float mean = s * (1.0f / Dl);
    const float rstd = rsqrtf(s2 * (1.0f / Dl) - mean * mean + 1e-5f);
    u16x4 pkH, pkL;
#pragma unroll
    for (int i = 0; i < 4; ++i) {
        const int col = tid * 4 + i;
        const float y = (vp[i] - mean) * rstd * g[col] + b[col];
        pkH[i] = f2b(y);
        pkL[i] = f2b(y - b2f(pkH[i]));
    }
    *(u16x4*)&outH[(size_t)row * Dl + tid * 4] = pkH;
    *(u16x4*)&outL[(size_t)row * Dl + tid * 4] = pkL;
}

// ---------------- LayerNorm + ReLU in-place on bf16, F=4096 ----------------
__global__ __launch_bounds__(256) void ln_relu_bf16(u16* __restrict__ mid,
                                                    const float* __restrict__ g,
                                                    const float* __restrict__ b) {
    constexpr int Fl = 4096;
    const int row = blockIdx.x, tid = threadIdx.x;
    u16* rp = mid + (size_t)row * Fl;
    float v[16];
    u32x4 raw[2];
#pragma unroll
    for (int c = 0; c < 2; ++c) raw[c] = *(const u32x4*)&rp[tid * 16 + c * 8];
#pragma unroll
    for (int c = 0; c < 2; ++c)
#pragma unroll
        for (int j = 0; j < 4; ++j) {
            const unsigned u = raw[c][j];
            v[c * 8 + j * 2] = __uint_as_float(u << 16);
            v[c * 8 + j * 2 + 1] = __uint_as_float(u & 0xffff0000u);
        }
    float s = 0.f, s2 = 0.f;
#pragma unroll
    for (int i = 0; i < 16; ++i) { s += v[i]; s2 += v[i] * v[i]; }
#pragma unroll
    for (int off = 32; off; off >>= 1) { s += __shfl_xor(s, off); s2 += __shfl_xor(s2, off); }
    __shared__ float red[8];
    const int lane = tid & 63, wid = tid >> 6;
    if (lane == 0) { red[wid] = s; red[4 + wid] = s2; }
    __syncthreads();
    s = red[0] + red[1] + red[2] + red[3];
    s2 = red[4] + red[5] + red[6] + red[7];
    const float mean = s * (1.0f / Fl);
    const float rstd = rsqrtf(s2 * (1.0f / Fl) - mean * mean + 1e-5f);
#pragma unroll
    for (int i = 0; i < 16; ++i) {
        const int col = tid * 16 + i;
        const float y = (v[i] - mean) * rstd * g[col] + b[col];
        rp[col] = f2b(fmaxf(y, 0.f));
    }
}

// ---------------- bf16 MFMA GEMM: C = A(MxK) * Bt(NxK)^T + bias ----------------
// EPI 0: bf16 row-major  1: f32 row-major  3: v -> [b][h][e][n]
template <int EPI>
__global__ __launch_bounds__(256, 2) void gemm_bf16(const u16* __restrict__ A,
                                                    const u16* __restrict__ Bt,
                                                    const float* __restrict__ bias,
                                                    u16* __restrict__ outB,
                                                    float* __restrict__ outF,
                                                    int M_, int N_, int K_) {
    constexpr int BM = 128, BN = 128, BK = 32, LDP = 40;
    __shared__ u16 As[BM * LDP];
    __shared__ u16 Bs[BN * LDP];
    const int tid = threadIdx.x;
    const int lane = tid & 63;
    const int wid = tid >> 6;
    const int m0 = blockIdx.y * BM;
    const int n0 = blockIdx.x * BN;
    const int wr = (wid >> 1) * 64;
    const int wc = (wid & 1) * 64;
    const int sr = tid >> 2;
    const int sc = (tid & 3) * 8;
    const int fr = lane & 15;
    const int fg = (lane >> 4) * 8;

    f32x4 acc[4][4] = {};

    const u16* pa0 = A + (size_t)(m0 + sr) * K_ + sc;
    const u16* pa1 = A + (size_t)(m0 + sr + 64) * K_ + sc;
    const u16* pb0 = Bt + (size_t)(n0 + sr) * K_ + sc;
    const u16* pb1 = Bt + (size_t)(n0 + sr + 64) * K_ + sc;

    for (int k0 = 0; k0 < K_; k0 += BK) {
        const u32x4 a0 = *(const u32x4*)(pa0 + k0);
        const u32x4 a1 = *(const u32x4*)(pa1 + k0);
        const u32x4 b0 = *(const u32x4*)(pb0 + k0);
        const u32x4 b1 = *(const u32x4*)(pb1 + k0);
        __syncthreads();
        *(u32x4*)&As[sr * LDP + sc] = a0;
        *(u32x4*)&As[(sr + 64) * LDP + sc] = a1;
        *(u32x4*)&Bs[sr * LDP + sc] = b0;
        *(u32x4*)&Bs[(sr + 64) * LDP + sc] = b1;
        __syncthreads();
        bf16x8 aF[4], bF[4];
#pragma unroll
        for (int i = 0; i < 4; ++i)
            aF[i] = *(const bf16x8*)&As[(wr + i * 16 + fr) * LDP + fg];
#pragma unroll
        for (int i = 0; i < 4; ++i)
            bF[i] = *(const bf16x8*)&Bs[(wc + i * 16 + fr) * LDP + fg];
#pragma unroll
        for (int i = 0; i < 4; ++i)
#pragma unroll
            for (int j = 0; j < 4; ++j)
                acc[i][j] = __builtin_amdgcn_mfma_f32_16x16x32_bf16(aF[i], bF[j], acc[i][j], 0, 0, 0);
    }

    const int g4 = (lane >> 4) * 4;
#pragma unroll
    for (int i = 0; i < 4; ++i) {
#pragma unroll
        for (int j = 0; j < 4; ++j) {
            const int mb = m0 + wr + i * 16 + g4;
            const int nb = n0 + wc + j * 16 + fr;
            const float bv = bias[nb];
            if constexpr (EPI == 0) {
#pragma unroll
                for (int r = 0; r < 4; ++r)
                    outB[(size_t)(mb + r) * N_ + nb] = f2b(acc[i][j][r] + bv);
            } else if constexpr (EPI == 1) {
#pragma unroll
                for (int r = 0; r < 4; ++r)
                    outF[(size_t)(mb + r) * N_ + nb] = acc[i][j][r] + bv;
            } else {
                const int h = nb >> 6, e = nb & 63;
                const int b_ = mb >> 11, np = mb & 2047;
                u16x4 pk;
#pragma unroll
                for (int r = 0; r < 4; ++r) pk[r] = f2b(acc[i][j][r] + bv);
                *(u16x4*)&outB[((size_t)(b_ * 16 + h) * 64 + e) * 2048 + np] = pk;
            }
        }
    }
}

// ------------- split (double-bf16) GEMM for q/k: C = (Ah+Al)(Bh+Bl)^T + bias -------------
// output layout [b][h][n][e] as hi/lo bf16 pairs
__global__ __launch_bounds__(256, 2) void gemm_split_qk(const u16* __restrict__ Ah,
                                                        const u16* __restrict__ Al,
                                                        const u16* __restrict__ Bh,
                                                        const u16* __restrict__ Bl,
                                                        const float* __restrict__ bias,
                                                        u16* __restrict__ outH,
                                                        u16* __restrict__ outL,
                                                        int M_, int N_, int K_) {
    constexpr int BM = 128, BN = 128, BK = 32, LDP = 40;
    __shared__ u16 AsH[BM * LDP];
    __shared__ u16 AsL[BM * LDP];
    __shared__ u16 BsH[BN * LDP];
    __shared__ u16 BsL[BN * LDP];
    const int tid = threadIdx.x;
    const int lane = tid & 63;
    const int wid = tid >> 6;
    const int m0 = blockIdx.y * BM;
    const int n0 = blockIdx.x * BN;
    const int wr = (wid >> 1) * 64;
    const int wc = (wid & 1) * 64;
    const int sr = tid >> 2;
    const int sc = (tid & 3) * 8;
    const int fr = lane & 15;
    const int fg = (lane >> 4) * 8;

    f32x4 acc[4][4] = {};

    const size_t oa0 = (size_t)(m0 + sr) * K_ + sc;
    const size_t oa1 = (size_t)(m0 + sr + 64) * K_ + sc;
    const size_t ob0 = (size_t)(n0 + sr) * K_ + sc;
    const size_t ob1 = (size_t)(n0 + sr + 64) * K_ + sc;

    for (int k0 = 0; k0 < K_; k0 += BK) {
        const u32x4 ah0 = *(const u32x4*)(Ah + oa0 + k0);
        const u32x4 ah1 = *(const u32x4*)(Ah + oa1 + k0);
        const u32x4 al0 = *(const u32x4*)(Al + oa0 + k0);
        const u32x4 al1 = *(const u32x4*)(Al + oa1 + k0);
        const u32x4 bh0 = *(const u32x4*)(Bh + ob0 + k0);
        const u32x4 bh1 = *(const u32x4*)(Bh + ob1 + k0);
        const u32x4 bl0 = *(const u32x4*)(Bl + ob0 + k0);
        const u32x4 bl1 = *(const u32x4*)(Bl + ob1 + k0);
        __syncthreads();
        *(u32x4*)&AsH[sr * LDP + sc] = ah0;
        *(u32x4*)&AsH[(sr + 64) * LDP + sc] = ah1;
        *(u32x4*)&AsL[sr * LDP + sc] = al0;
        *(u32x4*)&AsL[(sr + 64) * LDP + sc] = al1;
        *(u32x4*)&BsH[sr * LDP + sc] = bh0;
        *(u32x4*)&BsH[(sr + 64) * LDP + sc] = bh1;
        *(u32x4*)&BsL[sr * LDP + sc] = bl0;
        *(u32x4*)&BsL[(sr + 64) * LDP + sc] = bl1;
        __syncthreads();
        bf16x8 aH[4], aL[4], bH[4], bL[4];
#pragma unroll
        for (int i = 0; i < 4; ++i) {
            aH[i] = *(const bf16x8*)&AsH[(wr + i * 16 + fr) * LDP + fg];
            aL[i] = *(const bf16x8*)&AsL[(wr + i * 16 + fr) * LDP + fg];
            bH[i] = *(const bf16x8*)&BsH[(wc + i * 16 + fr) * LDP + fg];
            bL[i] = *(const bf16x8*)&BsL[(wc + i * 16 + fr) * LDP + fg];
        }
#pragma unroll
        for (int i = 0; i < 4; ++i)
#pragma unroll
            for (int j = 0; j < 4; ++j) {
                acc[i][j] = __builtin_amdgcn_mfma_f32_16x16x32_bf16(aH[i], bH[j], acc[i][j], 0, 0, 0);
                acc[i][j] = __builtin_amdgcn_mfma_f32_16x16x32_bf16(aH[i], bL[j], acc[i][j], 0, 0, 0);
                acc[i][j] = __builtin_amdgcn_mfma_f32_16x16x32_bf16(aL[i], bH[j], acc[i][j], 0, 0, 0);
            }
    }

    const int g4 = (lane >> 4) * 4;
#pragma unroll
    for (int i = 0; i < 4; ++i) {
#pragma unroll
        for (int j = 0; j < 4; ++j) {
            const int mb = m0 + wr + i * 16 + g4;
            const int nb = n0 + wc + j * 16 + fr;
            const float bv = bias[nb];
            const int h = nb >> 6, e = nb & 63;
#pragma unroll
            for (int r = 0; r < 4; ++r) {
                const int m = mb + r;
                const size_t idx = ((size_t)((m >> 11) * 16 + h) * 2048 + (m & 2047)) * 64 + e;
                const float v = acc[i][j][r] + bv;
                const u16 hi = f2b(v);
                outH[idx] = hi;
                outL[idx] = f2b(v - b2f(hi));
            }
        }
    }
}

// ---------------- flash attention + residual: x2 = x + softmax(q k^T * 32) v ----------------
__global__ __launch_bounds__(256, 2) void attn_kernel(const u16* __restrict__ qH,
                                                      const u16* __restrict__ qL,
                                                      const u16* __restrict__ kH,
                                                      const u16* __restrict__ kL,
                                                      const u16* __restrict__ vt,
                                                      const float* __restrict__ x,
                                                      float* __restrict__ x2) {
    constexpr int N = 2048, E = 64;
    constexpr int LK = 72, LV = 136, LP = 136;
    __shared__ u16 KsH[128 * LK];
    __shared__ u16 KsL[128 * LK];
    __shared__ u16 Vs[64 * LV];
    __shared__ u16 Ps[4 * 16 * LP];

    const int tid = threadIdx.x;
    const int lane = tid & 63;
    const int wid = tid >> 6;
    const int bh = blockIdx.x >> 5;
    const int q0 = (blockIdx.x & 31) * 64;
    const u16* qhh = qH + (size_t)bh * N * E;
    const u16* qhl = qL + (size_t)bh * N * E;
    const u16* khh = kH + (size_t)bh * N * E;
    const u16* khl = kL + (size_t)bh * N * E;
    const u16* vh = vt + (size_t)bh * E * N;

    const int fr = lane & 15;
    const int fgrp = lane >> 4;
    const int fg8 = fgrp * 8;
    const int wbase = wid * 16 * LP;

    bf16x8 qfh[2], qfl[2];
#pragma unroll
    for (int ks = 0; ks < 2; ++ks) {
        const size_t off = (size_t)(q0 + wid * 16 + fr) * E + ks * 32 + fg8;
        qfh[ks] = *(const bf16x8*)&qhh[off];
        qfl[ks] = *(const bf16x8*)&qhl[off];
    }

    f32x4 o[4] = {};
    float mrow[4], lrow[4];
#pragma unroll
    for (int r = 0; r < 4; ++r) { mrow[r] = -1e30f; lrow[r] = 0.f; }

    for (int kv0 = 0; kv0 < N; kv0 += 128) {
        __syncthreads();
#pragma unroll
        for (int p = 0; p < 4; ++p) {
            const int ch = tid + 256 * p;
            const int rK = ch >> 3, cK = (ch & 7) * 8;
            *(u32x4*)&KsH[rK * LK + cK] = *(const u32x4*)&khh[(size_t)(kv0 + rK) * E + cK];
            *(u32x4*)&KsL[rK * LK + cK] = *(const u32x4*)&khl[(size_t)(kv0 + rK) * E + cK];
            const int rV = ch >> 4, cV = (ch & 15) * 8;
            *(u32x4*)&Vs[rV * LV + cV] = *(const u32x4*)&vh[(size_t)rV * N + kv0 + cV];
        }
        __syncthreads();

        f32x4 s[8] = {};
#pragma unroll
        for (int fn = 0; fn < 8; ++fn)
#pragma unroll
            for (int ks = 0; ks < 2; ++ks) {
                const bf16x8 kfh = *(const bf16x8*)&KsH[(fn * 16 + fr) * LK + ks * 32 + fg8];
                const bf16x8 kfl = *(const bf16x8*)&KsL[(fn * 16 + fr) * LK + ks * 32 + fg8];
                s[fn] = __builtin_amdgcn_mfma_f32_16x16x32_bf16(qfh[ks], kfh, s[fn], 0, 0, 0);
                s[fn] = __builtin_amdgcn_mfma_f32_16x16x32_bf16(qfh[ks], kfl, s[fn], 0, 0, 0);
                s[fn] = __builtin_amdgcn_mfma_f32_16x16x32_bf16(qfl[ks], kfh, s[fn], 0, 0, 0);
            }

        float fac[4], rs[4];
#pragma unroll
        for (int r = 0; r < 4; ++r) {
            float v = s[0][r];
#pragma unroll
            for (int fn = 1; fn < 8; ++fn) v = fmaxf(v, s[fn][r]);
#pragma unroll
            for (int off = 1; off < 16; off <<= 1) v = fmaxf(v, __shfl_xor(v, off));
            const float mnew = fmaxf(mrow[r], v * 32.f);
            fac[r] = __expf(mrow[r] - mnew);
            mrow[r] = mnew;
            lrow[r] *= fac[r];
            rs[r] = 0.f;
        }
#pragma unroll
        for (int fn = 0; fn < 8; ++fn)
#pragma unroll
            for (int r = 0; r < 4; ++r) {
                const float pv = __expf(s[fn][r] * 32.f - mrow[r]);
                rs[r] += pv;
                Ps[wbase + (fgrp * 4 + r) * LP + fn * 16 + fr] = f2b(pv);
            }
#pragma unroll
        for (int r = 0; r < 4; ++r) {
            float v = rs[r];
#pragma unroll
            for (int off = 1; off < 16; off <<= 1) v += __shfl_xor(v, off);
            lrow[r] += v;
#pragma unroll
            for (int fe = 0; fe < 4; ++fe) o[fe][r] *= fac[r];
        }

        bf16x8 pf[4];
#pragma unroll
        for (int ks = 0; ks < 4; ++ks)
            pf[ks] = *(const bf16x8*)&Ps[wbase + fr * LP + ks * 32 + fg8];
#pragma unroll
        for (int fe = 0; fe < 4; ++fe)
#pragma unroll
            for (int ks = 0; ks < 4; ++ks) {
                const bf16x8 vf = *(const bf16x8*)&Vs[(fe * 16 + fr) * LV + ks * 32 + fg8];
                o[fe] = __builtin_amdgcn_mfma_f32_16x16x32_bf16(pf[ks], vf, o[fe], 0, 0, 0);
            }
    }

    const int b_ = bh >> 4, h_ = bh & 15;
#pragma unroll
    for (int fe = 0; fe < 4; ++fe)
#pragma unroll
        for (int r = 0; r < 4; ++r) {
            const int npos = q0 + wid * 16 + fgrp * 4 + r;
            const size_t idx = ((size_t)(b_ * 2048 + npos)) * 1024 + h_ * 64 + fe * 16 + fr;
            x2[idx] = x[idx] + o[fe][r] / lrow[r];
        }
}

// ---------------- launch ----------------
extern "C" void kernel_launch(void* const* d_in, const int* in_sizes, int n_in,
                              void* d_out, int out_size, void* d_ws, size_t ws_size,
                              hipStream_t stream) {
    const float* x = (const float*)d_in[0];
    const float* wq = (const float*)d_in[1];
    const float* bq = (const float*)d_in[2];
    const float* wk = (const float*)d_in[3];
    const float* bk = (const float*)d_in[4];
    const float* wv = (const float*)d_in[5];
    const float* bv = (const float*)d_in[6];
    const float* g1 = (const float*)d_in[7];
    const float* b1 = (const float*)d_in[8];
    const float* g2 = (const float*)d_in[9];
    const float* b2 = (const float*)d_in[10];
    const float* w1 = (const float*)d_in[11];
    const float* bw1 = (const float*)d_in[12];
    const float* gf = (const float*)d_in[13];
    const float* bf = (const float*)d_in[14];
    const float* w2 = (const float*)d_in[15];
    const float* bw2 = (const float*)d_in[16];
    float* out = (float*)d_out;

    constexpr int Bc = 2, Nc = 2048, Dc = 1024, Fc = 4096, Mc = 4096;

    char* ws = (char*)d_ws;
    auto alloc = [&](size_t bytes) {
        char* p = ws;
        ws += (bytes + 255) & ~(size_t)255;
        return p;
    };
    u16* wqtH = (u16*)alloc((size_t)Dc * Dc * 2);
    u16* wqtL = (u16*)alloc((size_t)Dc * Dc * 2);
    u16* wktH = (u16*)alloc((size_t)Dc * Dc * 2);
    u16* wktL = (u16*)alloc((size_t)Dc * Dc * 2);
    u16* wvt = (u16*)alloc((size_t)Dc * Dc * 2);
    u16* w1t = (u16*)alloc((size_t)Dc * Fc * 2);
    u16* w2t = (u16*)alloc((size_t)Fc * Dc * 2);
    // region: h1H,h1L,qH,qL,kH,kL,vT (7 x 8MB = 56MB); mid (32MB) aliases the
    // first four chunks, all dead once attention has completed.
    char* region = (char*)alloc((size_t)Mc * Dc * 2 * 7);
    u16* h1H = (u16*)region;
    u16* h1L = h1H + (size_t)Mc * Dc;
    u16* qbH = h1L + (size_t)Mc * Dc;
    u16* qbL = qbH + (size_t)Mc * Dc;
    u16* kbH = qbL + (size_t)Mc * Dc;
    u16* kbL = kbH + (size_t)Mc * Dc;
    u16* vtb = kbL + (size_t)Mc * Dc;
    u16* mid = (u16*)region;
    float* x2 = (float*)alloc((size_t)Mc * Dc * 4);
    u16* h2 = (u16*)alloc((size_t)Mc * Dc * 2);

    const dim3 tb(32, 8);
    transpose_cast_split<<<dim3(Dc / 32, Dc / 32), tb, 0, stream>>>(wq, wqtH, wqtL, Dc, Dc);
    transpose_cast_split<<<dim3(Dc / 32, Dc / 32), tb, 0, stream>>>(wk, wktH, wktL, Dc, Dc);
    transpose_cast<<<dim3(Dc / 32, Dc / 32), tb, 0, stream>>>(wv, wvt, Dc, Dc);
    transpose_cast<<<dim3(Fc / 32, Dc / 32), tb, 0, stream>>>(w1, w1t, Dc, Fc);
    transpose_cast<<<dim3(Dc / 32, Fc / 32), tb, 0, stream>>>(w2, w2t, Fc, Dc);

    ln_f32_bf16_split<<<Mc, 256, 0, stream>>>(x, g1, b1, h1H, h1L);

    gemm_split_qk<<<dim3(Dc / 128, Mc / 128), 256, 0, stream>>>(h1H, h1L, wqtH, wqtL, bq, qbH, qbL, Mc, Dc, Dc);
    gemm_split_qk<<<dim3(Dc / 128, Mc / 128), 256, 0, stream>>>(h1H, h1L, wktH, wktL, bk, kbH, kbL, Mc, Dc, Dc);
    gemm_bf16<3><<<dim3(Dc / 128, Mc / 128), 256, 0, stream>>>(h1H, wvt, bv, vtb, nullptr, Mc, Dc, Dc);

    attn_kernel<<<Bc * 16 * (Nc / 64), 256, 0, stream>>>(qbH, qbL, kbH, kbL, vtb, x, x2);

    ln_f32_bf16<<<Mc, 256, 0, stream>>>(x2, g2, b2, h2);

    gemm_bf16<0><<<dim3(Fc / 128, Mc / 128), 256, 0, stream>>>(h2, w1t, bw1, mid, nullptr, Mc, Fc, Dc);

    ln_relu_bf16<<<Mc, 256, 0, stream>>>(mid, gf, bf);

    gemm_bf16<1><<<dim3(Dc / 128, Mc / 128), 256, 0, stream>>>(mid, w2t, bw2, nullptr, out, Mc, Dc, Fc);
}

// Round 3
// 434.344 us; speedup vs baseline: 1.0099x; 1.0099x over previous
//
#include <hip/hip_runtime.h>

typedef unsigned short u16;
typedef short bf16x8 __attribute__((ext_vector_type(8)));
typedef float f32x4 __attribute__((ext_vector_type(4)));
typedef unsigned short u16x4 __attribute__((ext_vector_type(4)));
typedef unsigned int u32x4 __attribute__((ext_vector_type(4)));

__device__ __forceinline__ u16 f2b(float f) {
    unsigned u = __float_as_uint(f);
    u += 0x7fffu + ((u >> 16) & 1u);
    return (u16)(u >> 16);
}
__device__ __forceinline__ float b2f(u16 h) { return __uint_as_float((unsigned)h << 16); }

// async global -> LDS, 16B per lane; LDS dest is wave-uniform base + lane*16
__device__ __forceinline__ void gload16(const u16* g, u16* l) {
    __builtin_amdgcn_global_load_lds((const __attribute__((address_space(1))) unsigned int*)g,
                                     (__attribute__((address_space(3))) unsigned int*)l, 16, 0, 0);
}

// ---------------- transpose + cast fp32 -> bf16, Wt[n][k] = W[k][n] ----------------
__global__ void transpose_cast(const float* __restrict__ W, u16* __restrict__ Wt,
                               int K, int N) {
    __shared__ float t[32][33];
    const int n0 = blockIdx.x * 32, k0 = blockIdx.y * 32;
    const int tx = threadIdx.x, ty = threadIdx.y;
#pragma unroll
    for (int i = 0; i < 32; i += 8)
        t[ty + i][tx] = W[(size_t)(k0 + ty + i) * N + n0 + tx];
    __syncthreads();
#pragma unroll
    for (int i = 0; i < 32; i += 8)
        Wt[(size_t)(n0 + ty + i) * K + k0 + tx] = f2b(t[tx][ty + i]);
}

// ---------------- transpose + split cast fp32 -> bf16 hi/lo ----------------
__global__ void transpose_cast_split(const float* __restrict__ W, u16* __restrict__ WtH,
                                     u16* __restrict__ WtL, int K, int N) {
    __shared__ float t[32][33];
    const int n0 = blockIdx.x * 32, k0 = blockIdx.y * 32;
    const int tx = threadIdx.x, ty = threadIdx.y;
#pragma unroll
    for (int i = 0; i < 32; i += 8)
        t[ty + i][tx] = W[(size_t)(k0 + ty + i) * N + n0 + tx];
    __syncthreads();
#pragma unroll
    for (int i = 0; i < 32; i += 8) {
        const float v = t[tx][ty + i];
        const u16 hi = f2b(v);
        const size_t idx = (size_t)(n0 + ty + i) * K + k0 + tx;
        WtH[idx] = hi;
        WtL[idx] = f2b(v - b2f(hi));
    }
}

// ---------------- LayerNorm fp32 -> bf16, D=1024, one block per row ----------------
__global__ __launch_bounds__(256) void ln_f32_bf16(const float* __restrict__ in,
                                                   const float* __restrict__ g,
                                                   const float* __restrict__ b,
                                                   u16* __restrict__ out) {
    constexpr int Dl = 1024;
    const int row = blockIdx.x, tid = threadIdx.x;
    const float4 v = *(const float4*)&in[(size_t)row * Dl + tid * 4];
    const float* vp = (const float*)&v;
    float s = v.x + v.y + v.z + v.w;
    float s2 = v.x * v.x + v.y * v.y + v.z * v.z + v.w * v.w;
#pragma unroll
    for (int off = 32; off; off >>= 1) { s += __shfl_xor(s, off); s2 += __shfl_xor(s2, off); }
    __shared__ float red[8];
    const int lane = tid & 63, wid = tid >> 6;
    if (lane == 0) { red[wid] = s; red[4 + wid] = s2; }
    __syncthreads();
    s = red[0] + red[1] + red[2] + red[3];
    s2 = red[4] + red[5] + red[6] + red[7];
    const float mean = s * (1.0f / Dl);
    const float rstd = rsqrtf(s2 * (1.0f / Dl) - mean * mean + 1e-5f);
    u16x4 pk;
#pragma unroll
    for (int i = 0; i < 4; ++i) {
        const int col = tid * 4 + i;
        pk[i] = f2b((vp[i] - mean) * rstd * g[col] + b[col]);
    }
    *(u16x4*)&out[(size_t)row * Dl + tid * 4] = pk;
}

// ---------------- LayerNorm fp32 -> bf16 hi/lo pair ----------------
__global__ __launch_bounds__(256) void ln_f32_bf16_split(const float* __restrict__ in,
                                                         const float* __restrict__ g,
                                                         const float* __restrict__ b,
                                                         u16* __restrict__ outH,
                                                         u16* __restrict__ outL) {
    constexpr int Dl = 1024;
    const int row = blockIdx.x, tid = threadIdx.x;
    const float4 v = *(const float4*)&in[(size_t)row * Dl + tid * 4];
    const float* vp = (const float*)&v;
    float s = v.x + v.y + v.z + v.w;
    float s2 = v.x * v.x + v.y * v.y + v.z * v.z + v.w * v.w;
#pragma unroll
    for (int off = 32; off; off >>= 1) { s += __shfl_xor(s, off); s2 += __shfl_xor(s2, off); }
    __shared__ float red[8];
    const int lane = tid & 63, wid = tid >> 6;
    if (lane == 0) { red[wid] = s; red[4 + wid] = s2; }
    __syncthreads();
    s = red[0] + red[1] + red[2] + red[3];
    s2 = red[4] + red[5] + red[6] + red[7];
    const float mean = s * (1.0f / Dl);
    const float rstd = rsqrtf(s2 * (1.0f / Dl) - mean * mean + 1e-5f);
    u16x4 pkH, pkL;
#pragma unroll
    for (int i = 0; i < 4; ++i) {
        const int col = tid * 4 + i;
        const float y = (vp[i] - mean) * rstd * g[col] + b[col];
        pkH[i] = f2b(y);
        pkL[i] = f2b(y - b2f(pkH[i]));
    }
    *(u16x4*)&outH[(size_t)row * Dl + tid * 4] = pkH;
    *(u16x4*)&outL[(size_t)row * Dl + tid * 4] = pkL;
}

// ---------------- LayerNorm + ReLU in-place on bf16, F=4096 ----------------
__global__ __launch_bounds__(256) void ln_relu_bf16(u16* __restrict__ mid,
                                                    const float* __restrict__ g,
                                                    const float* __restrict__ b) {
    constexpr int Fl = 4096;
    const int row = blockIdx.x, tid = threadIdx.x;
    u16* rp = mid + (size_t)row * Fl;
    float v[16];
    u32x4 raw[2];
#pragma unroll
    for (int c = 0; c < 2; ++c) raw[c] = *(const u32x4*)&rp[tid * 16 + c * 8];
#pragma unroll
    for (int c = 0; c < 2; ++c)
#pragma unroll
        for (int j = 0; j < 4; ++j) {
            const unsigned u = raw[c][j];
            v[c * 8 + j * 2] = __uint_as_float(u << 16);
            v[c * 8 + j * 2 + 1] = __uint_as_float(u & 0xffff0000u);
        }
    float s = 0.f, s2 = 0.f;
#pragma unroll
    for (int i = 0; i < 16; ++i) { s += v[i]; s2 += v[i] * v[i]; }
#pragma unroll
    for (int off = 32; off; off >>= 1) { s += __shfl_xor(s, off); s2 += __shfl_xor(s2, off); }
    __shared__ float red[8];
    const int lane = tid & 63, wid = tid >> 6;
    if (lane == 0) { red[wid] = s; red[4 + wid] = s2; }
    __syncthreads();
    s = red[0] + red[1] + red[2] + red[3];
    s2 = red[4] + red[5] + red[6] + red[7];
    const float mean = s * (1.0f / Fl);
    const float rstd = rsqrtf(s2 * (1.0f / Fl) - mean * mean + 1e-5f);
#pragma unroll
    for (int i = 0; i < 16; ++i) {
        const int col = tid * 16 + i;
        const float y = (v[i] - mean) * rstd * g[col] + b[col];
        rp[col] = f2b(fmaxf(y, 0.f));
    }
}

// ---------------- bf16 MFMA GEMM (m97 structure): C = A(MxK) * Bt(NxK)^T + bias ----------------
// EPI 0: bf16 row-major  1: f32 row-major  3: v -> [b][h][e][n]
template <int EPI>
__global__ __launch_bounds__(256, 2) void gemm_bf16(const u16* __restrict__ A,
                                                    const u16* __restrict__ Bt,
                                                    const float* __restrict__ bias,
                                                    u16* __restrict__ outB,
                                                    float* __restrict__ outF,
                                                    int M_, int N_, int K_) {
    constexpr int BK = 32;
    __shared__ u16 As[128 * BK];
    __shared__ u16 Bs[128 * BK];
    const int tid = threadIdx.x;
    const int lane = tid & 63;
    const int wid = tid >> 6;
    const int m0 = blockIdx.y * 128;
    const int n0 = blockIdx.x * 128;
    const int wr = (wid >> 1) * 64;
    const int wc = (wid & 1) * 64;
    const int fr = lane & 15;
    const int fg = (lane >> 4) * 8;

    // staging: wave w covers rows [32w, 32w+32) of each tile; lane l -> row +(l>>2), col (l&3)*8
    const int srow = wid * 32 + (lane >> 2);
    const int scol = (lane & 3) * 8;
    const u16* pa0 = A + (size_t)(m0 + srow) * K_ + scol;
    const u16* pa1 = pa0 + (size_t)16 * K_;
    const u16* pb0 = Bt + (size_t)(n0 + srow) * K_ + scol;
    const u16* pb1 = pb0 + (size_t)16 * K_;
    u16* lA0 = As + wid * 1024;
    u16* lA1 = lA0 + 512;
    u16* lB0 = Bs + wid * 1024;
    u16* lB1 = lB0 + 512;

    f32x4 acc[4][4] = {};

    for (int k0 = 0; k0 < K_; k0 += BK) {
        __syncthreads();
        gload16(pa0, lA0); gload16(pa1, lA1);
        gload16(pb0, lB0); gload16(pb1, lB1);
        pa0 += BK; pa1 += BK; pb0 += BK; pb1 += BK;
        __syncthreads();
        bf16x8 aF[4], bF[4];
#pragma unroll
        for (int i = 0; i < 4; ++i) aF[i] = *(const bf16x8*)&As[(wr + i * 16 + fr) * BK + fg];
#pragma unroll
        for (int j = 0; j < 4; ++j) bF[j] = *(const bf16x8*)&Bs[(wc + j * 16 + fr) * BK + fg];
#pragma unroll
        for (int i = 0; i < 4; ++i)
#pragma unroll
            for (int j = 0; j < 4; ++j)
                acc[i][j] = __builtin_amdgcn_mfma_f32_16x16x32_bf16(aF[i], bF[j], acc[i][j], 0, 0, 0);
    }

    const int g4 = (lane >> 4) * 4;
#pragma unroll
    for (int i = 0; i < 4; ++i) {
#pragma unroll
        for (int j = 0; j < 4; ++j) {
            const int mb = m0 + wr + i * 16 + g4;
            const int nb = n0 + wc + j * 16 + fr;
            const float bv = bias[nb];
            if constexpr (EPI == 0) {
#pragma unroll
                for (int r = 0; r < 4; ++r)
                    outB[(size_t)(mb + r) * N_ + nb] = f2b(acc[i][j][r] + bv);
            } else if constexpr (EPI == 1) {
#pragma unroll
                for (int r = 0; r < 4; ++r)
                    outF[(size_t)(mb + r) * N_ + nb] = acc[i][j][r] + bv;
            } else {
                const int h = nb >> 6, e = nb & 63;
                const int b_ = mb >> 11, np = mb & 2047;
                u16x4 pk;
#pragma unroll
                for (int r = 0; r < 4; ++r) pk[r] = f2b(acc[i][j][r] + bv);
                *(u16x4*)&outB[((size_t)(b_ * 16 + h) * 64 + e) * 2048 + np] = pk;
            }
        }
    }
}

// ------------- split (double-bf16) GEMM for q/k, m97-style staging -------------
__global__ __launch_bounds__(256, 2) void gemm_split_qk(const u16* __restrict__ Ah,
                                                        const u16* __restrict__ Al,
                                                        const u16* __restrict__ Bh,
                                                        const u16* __restrict__ Bl,
                                                        const float* __restrict__ bias,
                                                        u16* __restrict__ outH,
                                                        u16* __restrict__ outL,
                                                        int M_, int N_, int K_) {
    constexpr int BK = 32;
    __shared__ u16 AsH[128 * BK];
    __shared__ u16 AsL[128 * BK];
    __shared__ u16 BsH[128 * BK];
    __shared__ u16 BsL[128 * BK];
    const int tid = threadIdx.x;
    const int lane = tid & 63;
    const int wid = tid >> 6;
    const int m0 = blockIdx.y * 128;
    const int n0 = blockIdx.x * 128;
    const int wr = (wid >> 1) * 64;
    const int wc = (wid & 1) * 64;
    const int fr = lane & 15;
    const int fg = (lane >> 4) * 8;

    const int srow = wid * 32 + (lane >> 2);
    const int scol = (lane & 3) * 8;
    const size_t oa = (size_t)(m0 + srow) * K_ + scol;
    const size_t ob = (size_t)(n0 + srow) * K_ + scol;
    const u16* pah0 = Ah + oa; const u16* pah1 = pah0 + (size_t)16 * K_;
    const u16* pal0 = Al + oa; const u16* pal1 = pal0 + (size_t)16 * K_;
    const u16* pbh0 = Bh + ob; const u16* pbh1 = pbh0 + (size_t)16 * K_;
    const u16* pbl0 = Bl + ob; const u16* pbl1 = pbl0 + (size_t)16 * K_;
    u16* lah0 = AsH + wid * 1024; u16* lah1 = lah0 + 512;
    u16* lal0 = AsL + wid * 1024; u16* lal1 = lal0 + 512;
    u16* lbh0 = BsH + wid * 1024; u16* lbh1 = lbh0 + 512;
    u16* lbl0 = BsL + wid * 1024; u16* lbl1 = lbl0 + 512;

    f32x4 acc[4][4] = {};

    for (int k0 = 0; k0 < K_; k0 += BK) {
        __syncthreads();
        gload16(pah0, lah0); gload16(pah1, lah1);
        gload16(pal0, lal0); gload16(pal1, lal1);
        gload16(pbh0, lbh0); gload16(pbh1, lbh1);
        gload16(pbl0, lbl0); gload16(pbl1, lbl1);
        pah0 += BK; pah1 += BK; pal0 += BK; pal1 += BK;
        pbh0 += BK; pbh1 += BK; pbl0 += BK; pbl1 += BK;
        __syncthreads();
        bf16x8 aH[4], aL[4], bH[4], bL[4];
#pragma unroll
        for (int i = 0; i < 4; ++i) {
            aH[i] = *(const bf16x8*)&AsH[(wr + i * 16 + fr) * BK + fg];
            aL[i] = *(const bf16x8*)&AsL[(wr + i * 16 + fr) * BK + fg];
            bH[i] = *(const bf16x8*)&BsH[(wc + i * 16 + fr) * BK + fg];
            bL[i] = *(const bf16x8*)&BsL[(wc + i * 16 + fr) * BK + fg];
        }
#pragma unroll
        for (int i = 0; i < 4; ++i)
#pragma unroll
            for (int j = 0; j < 4; ++j) {
                acc[i][j] = __builtin_amdgcn_mfma_f32_16x16x32_bf16(aH[i], bH[j], acc[i][j], 0, 0, 0);
                acc[i][j] = __builtin_amdgcn_mfma_f32_16x16x32_bf16(aH[i], bL[j], acc[i][j], 0, 0, 0);
                acc[i][j] = __builtin_amdgcn_mfma_f32_16x16x32_bf16(aL[i], bH[j], acc[i][j], 0, 0, 0);
            }
    }

    const int g4 = (lane >> 4) * 4;
#pragma unroll
    for (int i = 0; i < 4; ++i) {
#pragma unroll
        for (int j = 0; j < 4; ++j) {
            const int mb = m0 + wr + i * 16 + g4;
            const int nb = n0 + wc + j * 16 + fr;
            const float bv = bias[nb];
            const int h = nb >> 6, e = nb & 63;
#pragma unroll
            for (int r = 0; r < 4; ++r) {
                const int m = mb + r;
                const size_t idx = ((size_t)((m >> 11) * 16 + h) * 2048 + (m & 2047)) * 64 + e;
                const float v = acc[i][j][r] + bv;
                const u16 hi = f2b(v);
                outH[idx] = hi;
                outL[idx] = f2b(v - b2f(hi));
            }
        }
    }
}

// ---------------- flash attention + residual: x2 = x + softmax(q k^T * 32) v ----------------
// KVBLK=64; K/V staged via global_load_lds into XOR-swizzled linear [64][64] tiles.
__global__ __launch_bounds__(256, 4) void attn_kernel(const u16* __restrict__ qH,
                                                      const u16* __restrict__ qL,
                                                      const u16* __restrict__ kH,
                                                      const u16* __restrict__ kL,
                                                      const u16* __restrict__ vt,
                                                      const float* __restrict__ x,
                                                      float* __restrict__ x2) {
    constexpr int N = 2048, E = 64, KB = 64;
    constexpr float L2E = 1.4426950408889634f;
    __shared__ u16 KsH[64 * 64];
    __shared__ u16 KsL[64 * 64];
    __shared__ u16 Vs[64 * 64];
    __shared__ u16 Ps[4 * 16 * 72];

    const int tid = threadIdx.x;
    const int lane = tid & 63;
    const int wid = tid >> 6;
    const int bh = blockIdx.x >> 5;
    const int q0 = (blockIdx.x & 31) * 64;
    const u16* qhh = qH + (size_t)bh * N * E;
    const u16* qhl = qL + (size_t)bh * N * E;
    const u16* khh = kH + (size_t)bh * N * E;
    const u16* khl = kL + (size_t)bh * N * E;
    const u16* vh = vt + (size_t)bh * E * N;

    const int fr = lane & 15;
    const int fgrp = lane >> 4;
    const int fg8 = fgrp * 8;
    const int wbase = wid * 16 * 72;
    const int rq = fr & 7;
    // physical (swizzled) u16 col of the 8-elem fragment at logical col ks*32+fg8
    int pc[2];
#pragma unroll
    for (int ks = 0; ks < 2; ++ks) pc[ks] = 8 * (((ks << 2) + fgrp) ^ rq);

    // staging: wave w stages rows [16w,16w+16) of KsH/KsL/Vs; 2 gloads each.
    // pre-swizzled source col so linear LDS dest holds the swizzled layout.
    const int swc = 8 * ((lane & 7) ^ (lane >> 3));
    const int sr8 = wid * 16 + (lane >> 3);
    const u16* pKH0 = khh + (size_t)sr8 * E + swc; const u16* pKH1 = pKH0 + 8 * E;
    const u16* pKL0 = khl + (size_t)sr8 * E + swc; const u16* pKL1 = pKL0 + 8 * E;
    const u16* pV0 = vh + (size_t)sr8 * N + swc;   const u16* pV1 = pV0 + 8 * N;
    u16* lKH0 = KsH + wid * 16 * 64; u16* lKH1 = lKH0 + 8 * 64;
    u16* lKL0 = KsL + wid * 16 * 64; u16* lKL1 = lKL0 + 8 * 64;
    u16* lV0 = Vs + wid * 16 * 64;   u16* lV1 = lV0 + 8 * 64;

    // q fragments, pre-scaled by 32 (exact in bf16)
    bf16x8 qfh[2], qfl[2];
#pragma unroll
    for (int ks = 0; ks < 2; ++ks) {
        const size_t off = (size_t)(q0 + wid * 16 + fr) * E + ks * 32 + fg8;
        bf16x8 th = *(const bf16x8*)&qhh[off];
        bf16x8 tl = *(const bf16x8*)&qhl[off];
#pragma unroll
        for (int e = 0; e < 8; ++e) {
            th[e] = (short)f2b(b2f((u16)th[e]) * 32.f);
            tl[e] = (short)f2b(b2f((u16)tl[e]) * 32.f);
        }
        qfh[ks] = th;
        qfl[ks] = tl;
    }

    f32x4 o[4] = {};
    float mrow[4], lrow[4];
#pragma unroll
    for (int r = 0; r < 4; ++r) { mrow[r] = -1e30f; lrow[r] = 0.f; }

    for (int t = 0; t < N / KB; ++t) {
        __syncthreads();
        gload16(pKH0, lKH0); gload16(pKH1, lKH1);
        gload16(pKL0, lKL0); gload16(pKL1, lKL1);
        gload16(pV0, lV0);   gload16(pV1, lV1);
        pKH0 += KB * E; pKH1 += KB * E;
        pKL0 += KB * E; pKL1 += KB * E;
        pV0 += KB;      pV1 += KB;
        __syncthreads();

        f32x4 s[4] = {};
#pragma unroll
        for (int fn = 0; fn < 4; ++fn)
#pragma unroll
            for (int ks = 0; ks < 2; ++ks) {
                const int R = fn * 16 + fr;
                const bf16x8 kfh = *(const bf16x8*)&KsH[R * 64 + pc[ks]];
                const bf16x8 kfl = *(const bf16x8*)&KsL[R * 64 + pc[ks]];
                s[fn] = __builtin_amdgcn_mfma_f32_16x16x32_bf16(qfh[ks], kfh, s[fn], 0, 0, 0);
                s[fn] = __builtin_amdgcn_mfma_f32_16x16x32_bf16(qfh[ks], kfl, s[fn], 0, 0, 0);
                s[fn] = __builtin_amdgcn_mfma_f32_16x16x32_bf16(qfl[ks], kfh, s[fn], 0, 0, 0);
            }

        float vmax[4];
#pragma unroll
        for (int r = 0; r < 4; ++r) {
            float v = fmaxf(fmaxf(s[0][r], s[1][r]), fmaxf(s[2][r], s[3][r]));
#pragma unroll
            for (int off = 1; off < 16; off <<= 1) v = fmaxf(v, __shfl_xor(v, off));
            vmax[r] = v;
        }
        const int within = (vmax[0] <= mrow[0] + 8.f) && (vmax[1] <= mrow[1] + 8.f) &&
                           (vmax[2] <= mrow[2] + 8.f) && (vmax[3] <= mrow[3] + 8.f);
        if (!__all(within)) {
#pragma unroll
            for (int r = 0; r < 4; ++r) {
                const float mnew = fmaxf(mrow[r], vmax[r]);
                const float fac = exp2f((mrow[r] - mnew) * L2E);
                mrow[r] = mnew;
                lrow[r] *= fac;
#pragma unroll
                for (int fe = 0; fe < 4; ++fe) o[fe][r] *= fac;
            }
        }
        float rs[4], nml[4];
#pragma unroll
        for (int r = 0; r < 4; ++r) { rs[r] = 0.f; nml[r] = -mrow[r] * L2E; }
#pragma unroll
        for (int fn = 0; fn < 4; ++fn)
#pragma unroll
            for (int r = 0; r < 4; ++r) {
                const float p = exp2f(fmaf(s[fn][r], L2E, nml[r]));
                rs[r] += p;
                Ps[wbase + (fgrp * 4 + r) * 72 + fn * 16 + fr] = f2b(p);
            }
#pragma unroll
        for (int r = 0; r < 4; ++r) {
            float v = rs[r];
#pragma unroll
            for (int off = 1; off < 16; off <<= 1) v += __shfl_xor(v, off);
            lrow[r] += v;
        }

        bf16x8 pf[2];
#pragma unroll
        for (int ks = 0; ks < 2; ++ks)
            pf[ks] = *(const bf16x8*)&Ps[wbase + fr * 72 + ks * 32 + fg8];
#pragma unroll
        for (int fe = 0; fe < 4; ++fe)
#pragma unroll
            for (int ks = 0; ks < 2; ++ks) {
                const bf16x8 vf = *(const bf16x8*)&Vs[(fe * 16 + fr) * 64 + pc[ks]];
                o[fe] = __builtin_amdgcn_mfma_f32_16x16x32_bf16(pf[ks], vf, o[fe], 0, 0, 0);
            }
    }

    const int b_ = bh >> 4, h_ = bh & 15;
#pragma unroll
    for (int fe = 0; fe < 4; ++fe)
#pragma unroll
        for (int r = 0; r < 4; ++r) {
            const int npos = q0 + wid * 16 + fgrp * 4 + r;
            const size_t idx = ((size_t)(b_ * 2048 + npos)) * 1024 + h_ * 64 + fe * 16 + fr;
            x2[idx] = x[idx] + o[fe][r] / lrow[r];
        }
}

// ---------------- launch ----------------
extern "C" void kernel_launch(void* const* d_in, const int* in_sizes, int n_in,
                              void* d_out, int out_size, void* d_ws, size_t ws_size,
                              hipStream_t stream) {
    const float* x = (const float*)d_in[0];
    const float* wq = (const float*)d_in[1];
    const float* bq = (const float*)d_in[2];
    const float* wk = (const float*)d_in[3];
    const float* bk = (const float*)d_in[4];
    const float* wv = (const float*)d_in[5];
    const float* bv = (const float*)d_in[6];
    const float* g1 = (const float*)d_in[7];
    const float* b1 = (const float*)d_in[8];
    const float* g2 = (const float*)d_in[9];
    const float* b2 = (const float*)d_in[10];
    const float* w1 = (const float*)d_in[11];
    const float* bw1 = (const float*)d_in[12];
    const float* gf = (const float*)d_in[13];
    const float* bf = (const float*)d_in[14];
    const float* w2 = (const float*)d_in[15];
    const float* bw2 = (const float*)d_in[16];
    float* out = (float*)d_out;

    constexpr int Bc = 2, Nc = 2048, Dc = 1024, Fc = 4096, Mc = 4096;

    char* ws = (char*)d_ws;
    auto alloc = [&](size_t bytes) {
        char* p = ws;
        ws += (bytes + 255) & ~(size_t)255;
        return p;
    };
    u16* wqtH = (u16*)alloc((size_t)Dc * Dc * 2);
    u16* wqtL = (u16*)alloc((size_t)Dc * Dc * 2);
    u16* wktH = (u16*)alloc((size_t)Dc * Dc * 2);
    u16* wktL = (u16*)alloc((size_t)Dc * Dc * 2);
    u16* wvt = (u16*)alloc((size_t)Dc * Dc * 2);
    u16* w1t = (u16*)alloc((size_t)Dc * Fc * 2);
    u16* w2t = (u16*)alloc((size_t)Fc * Dc * 2);
    char* region = (char*)alloc((size_t)Mc * Dc * 2 * 7);
    u16* h1H = (u16*)region;
    u16* h1L = h1H + (size_t)Mc * Dc;
    u16* qbH = h1L + (size_t)Mc * Dc;
    u16* qbL = qbH + (size_t)Mc * Dc;
    u16* kbH = qbL + (size_t)Mc * Dc;
    u16* kbL = kbH + (size_t)Mc * Dc;
    u16* vtb = kbL + (size_t)Mc * Dc;
    u16* mid = (u16*)region;  // alias: h1/q/k dead once attention is done
    float* x2 = (float*)alloc((size_t)Mc * Dc * 4);
    u16* h2 = (u16*)alloc((size_t)Mc * Dc * 2);

    const dim3 tb(32, 8);
    transpose_cast_split<<<dim3(Dc / 32, Dc / 32), tb, 0, stream>>>(wq, wqtH, wqtL, Dc, Dc);
    transpose_cast_split<<<dim3(Dc / 32, Dc / 32), tb, 0, stream>>>(wk, wktH, wktL, Dc, Dc);
    transpose_cast<<<dim3(Dc / 32, Dc / 32), tb, 0, stream>>>(wv, wvt, Dc, Dc);
    transpose_cast<<<dim3(Fc / 32, Dc / 32), tb, 0, stream>>>(w1, w1t, Dc, Fc);
    transpose_cast<<<dim3(Dc / 32, Fc / 32), tb, 0, stream>>>(w2, w2t, Fc, Dc);

    ln_f32_bf16_split<<<Mc, 256, 0, stream>>>(x, g1, b1, h1H, h1L);

    gemm_split_qk<<<dim3(Dc / 128, Mc / 128), 256, 0, stream>>>(h1H, h1L, wqtH, wqtL, bq, qbH, qbL, Mc, Dc, Dc);
    gemm_split_qk<<<dim3(Dc / 128, Mc / 128), 256, 0, stream>>>(h1H, h1L, wktH, wktL, bk, kbH, kbL, Mc, Dc, Dc);
    gemm_bf16<3><<<dim3(Dc / 128, Mc / 128), 256, 0, stream>>>(h1H, wvt, bv, vtb, nullptr, Mc, Dc, Dc);

    attn_kernel<<<Bc * 16 * (Nc / 64), 256, 0, stream>>>(qbH, qbL, kbH, kbL, vtb, x, x2);

    ln_f32_bf16<<<Mc, 256, 0, stream>>>(x2, g2, b2, h2);

    gemm_bf16<0><<<dim3(Fc / 128, Mc / 128), 256, 0, stream>>>(h2, w1t, bw1, mid, nullptr, Mc, Fc, Dc);

    ln_relu_bf16<<<Mc, 256, 0, stream>>>(mid, gf, bf);

    gemm_bf16<1><<<dim3(Dc / 128, Mc / 128), 256, 0, stream>>>(mid, w2t, bw2, nullptr, out, Mc, Dc, Fc);
}

// Round 4
// 374.953 us; speedup vs baseline: 1.1699x; 1.1584x over previous
//
#include <hip/hip_runtime.h>

typedef unsigned short u16;
typedef short bf16x8 __attribute__((ext_vector_type(8)));
typedef float f32x4 __attribute__((ext_vector_type(4)));
typedef unsigned short u16x4 __attribute__((ext_vector_type(4)));
typedef unsigned int u32x4 __attribute__((ext_vector_type(4)));

__device__ __forceinline__ u16 f2b(float f) {
    unsigned u = __float_as_uint(f);
    u += 0x7fffu + ((u >> 16) & 1u);
    return (u16)(u >> 16);
}
__device__ __forceinline__ float b2f(u16 h) { return __uint_as_float((unsigned)h << 16); }

// async global -> LDS, 16B per lane; LDS dest is wave-uniform base + lane*16
__device__ __forceinline__ void gload16(const u16* g, u16* l) {
    __builtin_amdgcn_global_load_lds((const __attribute__((address_space(1))) unsigned int*)g,
                                     (__attribute__((address_space(3))) unsigned int*)l, 16, 0, 0);
}

// ---------------- transpose + cast fp32 -> bf16, Wt[n][k] = W[k][n] ----------------
__global__ void transpose_cast(const float* __restrict__ W, u16* __restrict__ Wt,
                               int K, int N) {
    __shared__ float t[32][33];
    const int n0 = blockIdx.x * 32, k0 = blockIdx.y * 32;
    const int tx = threadIdx.x, ty = threadIdx.y;
#pragma unroll
    for (int i = 0; i < 32; i += 8)
        t[ty + i][tx] = W[(size_t)(k0 + ty + i) * N + n0 + tx];
    __syncthreads();
#pragma unroll
    for (int i = 0; i < 32; i += 8)
        Wt[(size_t)(n0 + ty + i) * K + k0 + tx] = f2b(t[tx][ty + i]);
}

// ---------------- transpose + split cast fp32 -> bf16 hi/lo ----------------
__global__ void transpose_cast_split(const float* __restrict__ W, u16* __restrict__ WtH,
                                     u16* __restrict__ WtL, int K, int N) {
    __shared__ float t[32][33];
    const int n0 = blockIdx.x * 32, k0 = blockIdx.y * 32;
    const int tx = threadIdx.x, ty = threadIdx.y;
#pragma unroll
    for (int i = 0; i < 32; i += 8)
        t[ty + i][tx] = W[(size_t)(k0 + ty + i) * N + n0 + tx];
    __syncthreads();
#pragma unroll
    for (int i = 0; i < 32; i += 8) {
        const float v = t[tx][ty + i];
        const u16 hi = f2b(v);
        const size_t idx = (size_t)(n0 + ty + i) * K + k0 + tx;
        WtH[idx] = hi;
        WtL[idx] = f2b(v - b2f(hi));
    }
}

// ---------------- LayerNorm fp32 -> bf16, D=1024, one block per row ----------------
__global__ __launch_bounds__(256) void ln_f32_bf16(const float* __restrict__ in,
                                                   const float* __restrict__ g,
                                                   const float* __restrict__ b,
                                                   u16* __restrict__ out) {
    constexpr int Dl = 1024;
    const int row = blockIdx.x, tid = threadIdx.x;
    const float4 v = *(const float4*)&in[(size_t)row * Dl + tid * 4];
    const float* vp = (const float*)&v;
    float s = v.x + v.y + v.z + v.w;
    float s2 = v.x * v.x + v.y * v.y + v.z * v.z + v.w * v.w;
#pragma unroll
    for (int off = 32; off; off >>= 1) { s += __shfl_xor(s, off); s2 += __shfl_xor(s2, off); }
    __shared__ float red[8];
    const int lane = tid & 63, wid = tid >> 6;
    if (lane == 0) { red[wid] = s; red[4 + wid] = s2; }
    __syncthreads();
    s = red[0] + red[1] + red[2] + red[3];
    s2 = red[4] + red[5] + red[6] + red[7];
    const float mean = s * (1.0f / Dl);
    const float rstd = rsqrtf(s2 * (1.0f / Dl) - mean * mean + 1e-5f);
    u16x4 pk;
#pragma unroll
    for (int i = 0; i < 4; ++i) {
        const int col = tid * 4 + i;
        pk[i] = f2b((vp[i] - mean) * rstd * g[col] + b[col]);
    }
    *(u16x4*)&out[(size_t)row * Dl + tid * 4] = pk;
}

// ---------------- LayerNorm fp32 -> bf16 hi/lo pair ----------------
__global__ __launch_bounds__(256) void ln_f32_bf16_split(const float* __restrict__ in,
                                                         const float* __restrict__ g,
                                                         const float* __restrict__ b,
                                                         u16* __restrict__ outH,
                                                         u16* __restrict__ outL) {
    constexpr int Dl = 1024;
    const int row = blockIdx.x, tid = threadIdx.x;
    const float4 v = *(const float4*)&in[(size_t)row * Dl + tid * 4];
    const float* vp = (const float*)&v;
    float s = v.x + v.y + v.z + v.w;
    float s2 = v.x * v.x + v.y * v.y + v.z * v.z + v.w * v.w;
#pragma unroll
    for (int off = 32; off; off >>= 1) { s += __shfl_xor(s, off); s2 += __shfl_xor(s2, off); }
    __shared__ float red[8];
    const int lane = tid & 63, wid = tid >> 6;
    if (lane == 0) { red[wid] = s; red[4 + wid] = s2; }
    __syncthreads();
    s = red[0] + red[1] + red[2] + red[3];
    s2 = red[4] + red[5] + red[6] + red[7];
    const float mean = s * (1.0f / Dl);
    const float rstd = rsqrtf(s2 * (1.0f / Dl) - mean * mean + 1e-5f);
    u16x4 pkH, pkL;
#pragma unroll
    for (int i = 0; i < 4; ++i) {
        const int col = tid * 4 + i;
        const float y = (vp[i] - mean) * rstd * g[col] + b[col];
        pkH[i] = f2b(y);
        pkL[i] = f2b(y - b2f(pkH[i]));
    }
    *(u16x4*)&outH[(size_t)row * Dl + tid * 4] = pkH;
    *(u16x4*)&outL[(size_t)row * Dl + tid * 4] = pkL;
}

// ---------------- LayerNorm + ReLU in-place on bf16, F=4096 ----------------
__global__ __launch_bounds__(256) void ln_relu_bf16(u16* __restrict__ mid,
                                                    const float* __restrict__ g,
                                                    const float* __restrict__ b) {
    constexpr int Fl = 4096;
    const int row = blockIdx.x, tid = threadIdx.x;
    u16* rp = mid + (size_t)row * Fl;
    float v[16];
    u32x4 raw[2];
#pragma unroll
    for (int c = 0; c < 2; ++c) raw[c] = *(const u32x4*)&rp[tid * 16 + c * 8];
#pragma unroll
    for (int c = 0; c < 2; ++c)
#pragma unroll
        for (int j = 0; j < 4; ++j) {
            const unsigned u = raw[c][j];
            v[c * 8 + j * 2] = __uint_as_float(u << 16);
            v[c * 8 + j * 2 + 1] = __uint_as_float(u & 0xffff0000u);
        }
    float s = 0.f, s2 = 0.f;
#pragma unroll
    for (int i = 0; i < 16; ++i) { s += v[i]; s2 += v[i] * v[i]; }
#pragma unroll
    for (int off = 32; off; off >>= 1) { s += __shfl_xor(s, off); s2 += __shfl_xor(s2, off); }
    __shared__ float red[8];
    const int lane = tid & 63, wid = tid >> 6;
    if (lane == 0) { red[wid] = s; red[4 + wid] = s2; }
    __syncthreads();
    s = red[0] + red[1] + red[2] + red[3];
    s2 = red[4] + red[5] + red[6] + red[7];
    const float mean = s * (1.0f / Fl);
    const float rstd = rsqrtf(s2 * (1.0f / Fl) - mean * mean + 1e-5f);
#pragma unroll
    for (int i = 0; i < 16; ++i) {
        const int col = tid * 16 + i;
        const float y = (v[i] - mean) * rstd * g[col] + b[col];
        rp[col] = f2b(fmaxf(y, 0.f));
    }
}

// ---------------- bf16 MFMA GEMM: C = A(MxK) * Bt(NxK)^T + bias ----------------
// EPI 0: bf16 row-major  1: f32 row-major  3: v -> [b][h][e][n]
// BN = 128 (4 blocks/CU shapes) or 64 (doubles grid for N=1024 GEMMs)
template <int EPI, int BN>
__global__ __launch_bounds__(256, 2) void gemm_bf16(const u16* __restrict__ A,
                                                    const u16* __restrict__ Bt,
                                                    const float* __restrict__ bias,
                                                    u16* __restrict__ outB,
                                                    float* __restrict__ outF,
                                                    int M_, int N_, int K_) {
    constexpr int BK = 32;
    constexpr int NJ = BN / 32;  // B fragments per wave
    __shared__ u16 As[128 * BK];
    __shared__ u16 Bs[BN * BK];
    const int tid = threadIdx.x;
    const int lane = tid & 63;
    const int wid = tid >> 6;
    const int m0 = blockIdx.y * 128;
    const int n0 = blockIdx.x * BN;
    const int wr = (wid >> 1) * 64;
    const int wc = (wid & 1) * (BN / 2);
    const int fr = lane & 15;
    const int fg = (lane >> 4) * 8;

    const int srow = wid * 32 + (lane >> 2);
    const int srB = wid * (BN / 4) + (lane >> 2);
    const int scol = (lane & 3) * 8;
    const u16* pa0 = A + (size_t)(m0 + srow) * K_ + scol;
    const u16* pa1 = pa0 + (size_t)16 * K_;
    const u16* pb0 = Bt + (size_t)(n0 + srB) * K_ + scol;
    const u16* pb1 = pb0 + (size_t)16 * K_;
    u16* lA0 = As + wid * 1024;
    u16* lA1 = lA0 + 512;
    u16* lB0 = Bs + wid * (BN / 4) * BK;
    u16* lB1 = lB0 + 512;

    f32x4 acc[4][NJ] = {};

    for (int k0 = 0; k0 < K_; k0 += BK) {
        __syncthreads();
        gload16(pa0, lA0); gload16(pa1, lA1);
        gload16(pb0, lB0);
        if constexpr (BN == 128) gload16(pb1, lB1);
        pa0 += BK; pa1 += BK; pb0 += BK; pb1 += BK;
        __syncthreads();
        bf16x8 aF[4], bF[NJ];
#pragma unroll
        for (int i = 0; i < 4; ++i) aF[i] = *(const bf16x8*)&As[(wr + i * 16 + fr) * BK + fg];
#pragma unroll
        for (int j = 0; j < NJ; ++j) bF[j] = *(const bf16x8*)&Bs[(wc + j * 16 + fr) * BK + fg];
#pragma unroll
        for (int i = 0; i < 4; ++i)
#pragma unroll
            for (int j = 0; j < NJ; ++j)
                acc[i][j] = __builtin_amdgcn_mfma_f32_16x16x32_bf16(aF[i], bF[j], acc[i][j], 0, 0, 0);
    }

    const int g4 = (lane >> 4) * 4;
#pragma unroll
    for (int i = 0; i < 4; ++i) {
#pragma unroll
        for (int j = 0; j < NJ; ++j) {
            const int mb = m0 + wr + i * 16 + g4;
            const int nb = n0 + wc + j * 16 + fr;
            const float bv = bias[nb];
            if constexpr (EPI == 0) {
#pragma unroll
                for (int r = 0; r < 4; ++r)
                    outB[(size_t)(mb + r) * N_ + nb] = f2b(acc[i][j][r] + bv);
            } else if constexpr (EPI == 1) {
#pragma unroll
                for (int r = 0; r < 4; ++r)
                    outF[(size_t)(mb + r) * N_ + nb] = acc[i][j][r] + bv;
            } else {
                const int h = nb >> 6, e = nb & 63;
                const int b_ = mb >> 11, np = mb & 2047;
                u16x4 pk;
#pragma unroll
                for (int r = 0; r < 4; ++r) pk[r] = f2b(acc[i][j][r] + bv);
                *(u16x4*)&outB[((size_t)(b_ * 16 + h) * 64 + e) * 2048 + np] = pk;
            }
        }
    }
}

// ------------- split (double-bf16) GEMM for q/k, BN=64, out [b][h][n][e] hi/lo -------------
__global__ __launch_bounds__(256, 2) void gemm_split_qk(const u16* __restrict__ Ah,
                                                        const u16* __restrict__ Al,
                                                        const u16* __restrict__ Bh,
                                                        const u16* __restrict__ Bl,
                                                        const float* __restrict__ bias,
                                                        u16* __restrict__ outH,
                                                        u16* __restrict__ outL,
                                                        int M_, int N_, int K_) {
    constexpr int BK = 32;
    __shared__ u16 AsH[128 * BK];
    __shared__ u16 AsL[128 * BK];
    __shared__ u16 BsH[64 * BK];
    __shared__ u16 BsL[64 * BK];
    const int tid = threadIdx.x;
    const int lane = tid & 63;
    const int wid = tid >> 6;
    const int m0 = blockIdx.y * 128;
    const int n0 = blockIdx.x * 64;
    const int wr = (wid >> 1) * 64;
    const int wc = (wid & 1) * 32;
    const int fr = lane & 15;
    const int fg = (lane >> 4) * 8;

    const int srow = wid * 32 + (lane >> 2);
    const int srB = wid * 16 + (lane >> 2);
    const int scol = (lane & 3) * 8;
    const size_t oa = (size_t)(m0 + srow) * K_ + scol;
    const size_t ob = (size_t)(n0 + srB) * K_ + scol;
    const u16* pah0 = Ah + oa; const u16* pah1 = pah0 + (size_t)16 * K_;
    const u16* pal0 = Al + oa; const u16* pal1 = pal0 + (size_t)16 * K_;
    const u16* pbh = Bh + ob;
    const u16* pbl = Bl + ob;
    u16* lah0 = AsH + wid * 1024; u16* lah1 = lah0 + 512;
    u16* lal0 = AsL + wid * 1024; u16* lal1 = lal0 + 512;
    u16* lbh = BsH + wid * 512;
    u16* lbl = BsL + wid * 512;

    f32x4 acc[4][2] = {};

    for (int k0 = 0; k0 < K_; k0 += BK) {
        __syncthreads();
        gload16(pah0, lah0); gload16(pah1, lah1);
        gload16(pal0, lal0); gload16(pal1, lal1);
        gload16(pbh, lbh);   gload16(pbl, lbl);
        pah0 += BK; pah1 += BK; pal0 += BK; pal1 += BK;
        pbh += BK; pbl += BK;
        __syncthreads();
        bf16x8 aH[4], aL[4], bH[2], bL[2];
#pragma unroll
        for (int i = 0; i < 4; ++i) {
            aH[i] = *(const bf16x8*)&AsH[(wr + i * 16 + fr) * BK + fg];
            aL[i] = *(const bf16x8*)&AsL[(wr + i * 16 + fr) * BK + fg];
        }
#pragma unroll
        for (int j = 0; j < 2; ++j) {
            bH[j] = *(const bf16x8*)&BsH[(wc + j * 16 + fr) * BK + fg];
            bL[j] = *(const bf16x8*)&BsL[(wc + j * 16 + fr) * BK + fg];
        }
#pragma unroll
        for (int i = 0; i < 4; ++i)
#pragma unroll
            for (int j = 0; j < 2; ++j) {
                acc[i][j] = __builtin_amdgcn_mfma_f32_16x16x32_bf16(aH[i], bH[j], acc[i][j], 0, 0, 0);
                acc[i][j] = __builtin_amdgcn_mfma_f32_16x16x32_bf16(aH[i], bL[j], acc[i][j], 0, 0, 0);
                acc[i][j] = __builtin_amdgcn_mfma_f32_16x16x32_bf16(aL[i], bH[j], acc[i][j], 0, 0, 0);
            }
    }

    const int g4 = (lane >> 4) * 4;
#pragma unroll
    for (int i = 0; i < 4; ++i) {
#pragma unroll
        for (int j = 0; j < 2; ++j) {
            const int mb = m0 + wr + i * 16 + g4;
            const int nb = n0 + wc + j * 16 + fr;
            const float bv = bias[nb];
            const int h = nb >> 6, e = nb & 63;
#pragma unroll
            for (int r = 0; r < 4; ++r) {
                const int m = mb + r;
                const size_t idx = ((size_t)((m >> 11) * 16 + h) * 2048 + (m & 2047)) * 64 + e;
                const float v = acc[i][j][r] + bv;
                const u16 hi = f2b(v);
                outH[idx] = hi;
                outL[idx] = f2b(v - b2f(hi));
            }
        }
    }
}

// ---------------- flash attention + residual: x2 = x + softmax(q k^T * 32) v ----------------
// 512 threads / 128 q-rows per block; KVBLK=64 double-buffered via global_load_lds
// with counted vmcnt(3); XOR-swizzled K/V tiles; deferred row-sum; lane-local defer-max.
__global__ __launch_bounds__(512, 4) void attn_kernel(const u16* __restrict__ qH,
                                                      const u16* __restrict__ qL,
                                                      const u16* __restrict__ kH,
                                                      const u16* __restrict__ kL,
                                                      const u16* __restrict__ vt,
                                                      const float* __restrict__ x,
                                                      float* __restrict__ x2) {
    constexpr int N = 2048, E = 64, KB = 64, NT = N / KB;
    constexpr float L2E = 1.4426950408889634f;
    __shared__ u16 KsH[2][64 * 64];
    __shared__ u16 KsL[2][64 * 64];
    __shared__ u16 Vs[2][64 * 64];
    __shared__ u16 Ps[8 * 16 * 72];

    const int tid = threadIdx.x;
    const int lane = tid & 63;
    const int wid = tid >> 6;
    const int bh = blockIdx.x >> 4;
    const int q0 = (blockIdx.x & 15) * 128;
    const u16* qhh = qH + (size_t)bh * N * E;
    const u16* qhl = qL + (size_t)bh * N * E;
    const u16* khh = kH + (size_t)bh * N * E;
    const u16* khl = kL + (size_t)bh * N * E;
    const u16* vh = vt + (size_t)bh * E * N;

    const int fr = lane & 15;
    const int fgrp = lane >> 4;
    const int fg8 = fgrp * 8;
    const int wbase = wid * 16 * 72;
    // physical (swizzled) u16 col of the 8-elem fragment at logical col block ks*4+fgrp, row R
    int pc[2];
#pragma unroll
    for (int ks = 0; ks < 2; ++ks) pc[ks] = 8 * (((ks << 2) + fgrp) ^ (fr & 7));

    // staging geometry: wave w stages rows [8w, 8w+8) of KsH/KsL/Vs (1 gload each)
    const int srow = wid * 8 + (lane >> 3);
    const int swc = 8 * ((lane & 7) ^ (lane >> 3));  // pre-swizzled source col
    u16* dKH = &KsH[0][wid * 8 * 64];
    u16* dKL = &KsL[0][wid * 8 * 64];
    u16* dV = &Vs[0][wid * 8 * 64];
    constexpr int BUFO = 64 * 64;

    // q fragments, pre-scaled by 32 (exact in bf16)
    bf16x8 qfh[2], qfl[2];
#pragma unroll
    for (int ks = 0; ks < 2; ++ks) {
        const size_t off = (size_t)(q0 + wid * 16 + fr) * E + ks * 32 + fg8;
        bf16x8 th = *(const bf16x8*)&qhh[off];
        bf16x8 tl = *(const bf16x8*)&qhl[off];
#pragma unroll
        for (int e = 0; e < 8; ++e) {
            th[e] = (short)f2b(b2f((u16)th[e]) * 32.f);
            tl[e] = (short)f2b(b2f((u16)tl[e]) * 32.f);
        }
        qfh[ks] = th;
        qfl[ks] = tl;
    }

    auto stage = [&](int t, int buf) {
        const size_t kb = (size_t)t * KB;
        gload16(khh + (kb + srow) * E + swc, dKH + buf * BUFO);
        gload16(khl + (kb + srow) * E + swc, dKL + buf * BUFO);
        gload16(vh + (size_t)srow * N + kb + swc, dV + buf * BUFO);
    };

    f32x4 o[4] = {};
    float mrow[4], lpart[4];
#pragma unroll
    for (int r = 0; r < 4; ++r) { mrow[r] = -1e30f; lpart[r] = 0.f; }

    stage(0, 0);

    for (int t = 0; t < NT; ++t) {
        const int buf = t & 1;
        __syncthreads();  // all reads of buf^1 (prev tile) done -> safe to overwrite
        if (t + 1 < NT) {
            stage(t + 1, buf ^ 1);
            asm volatile("s_waitcnt vmcnt(3)" ::: "memory");  // tile t landed; t+1 in flight
        } else {
            asm volatile("s_waitcnt vmcnt(0)" ::: "memory");
        }
        __syncthreads();  // tile t visible to all waves

        const u16* KH = &KsH[buf][0];
        const u16* KL = &KsL[buf][0];
        const u16* VV = &Vs[buf][0];

        f32x4 s[4] = {};
#pragma unroll
        for (int fn = 0; fn < 4; ++fn)
#pragma unroll
            for (int ks = 0; ks < 2; ++ks) {
                const int R = fn * 16 + fr;
                const bf16x8 kfh = *(const bf16x8*)&KH[R * 64 + pc[ks]];
                const bf16x8 kfl = *(const bf16x8*)&KL[R * 64 + pc[ks]];
                s[fn] = __builtin_amdgcn_mfma_f32_16x16x32_bf16(qfh[ks], kfh, s[fn], 0, 0, 0);
                s[fn] = __builtin_amdgcn_mfma_f32_16x16x32_bf16(qfh[ks], kfl, s[fn], 0, 0, 0);
                s[fn] = __builtin_amdgcn_mfma_f32_16x16x32_bf16(qfl[ks], kfh, s[fn], 0, 0, 0);
            }

        // lane-local defer-max check: no cross-lane traffic in the common case
        float lmax[4];
#pragma unroll
        for (int r = 0; r < 4; ++r)
            lmax[r] = fmaxf(fmaxf(s[0][r], s[1][r]), fmaxf(s[2][r], s[3][r]));
        const int ok = (lmax[0] <= mrow[0] + 8.f) && (lmax[1] <= mrow[1] + 8.f) &&
                       (lmax[2] <= mrow[2] + 8.f) && (lmax[3] <= mrow[3] + 8.f);
        if (!__all(ok)) {
#pragma unroll
            for (int r = 0; r < 4; ++r) {
                float v = lmax[r];
#pragma unroll
                for (int off = 1; off < 16; off <<= 1) v = fmaxf(v, __shfl_xor(v, off));
                const float mnew = fmaxf(mrow[r], v);
                const float fac = exp2f((mrow[r] - mnew) * L2E);
                mrow[r] = mnew;
                lpart[r] *= fac;
#pragma unroll
                for (int fe = 0; fe < 4; ++fe) o[fe][r] *= fac;
            }
        }

        float rs[4], nml[4];
#pragma unroll
        for (int r = 0; r < 4; ++r) { rs[r] = 0.f; nml[r] = -mrow[r] * L2E; }
#pragma unroll
        for (int fn = 0; fn < 4; ++fn)
#pragma unroll
            for (int r = 0; r < 4; ++r) {
                const float p = exp2f(fmaf(s[fn][r], L2E, nml[r]));
                rs[r] += p;
                Ps[wbase + (fgrp * 4 + r) * 72 + fn * 16 + fr] = f2b(p);
            }
#pragma unroll
        for (int r = 0; r < 4; ++r) lpart[r] += rs[r];  // deferred: no shuffle here

        bf16x8 pf[2];
#pragma unroll
        for (int ks = 0; ks < 2; ++ks)
            pf[ks] = *(const bf16x8*)&Ps[wbase + fr * 72 + ks * 32 + fg8];
#pragma unroll
        for (int fe = 0; fe < 4; ++fe)
#pragma unroll
            for (int ks = 0; ks < 2; ++ks) {
                const bf16x8 vf = *(const bf16x8*)&VV[(fe * 16 + fr) * 64 + pc[ks]];
                o[fe] = __builtin_amdgcn_mfma_f32_16x16x32_bf16(pf[ks], vf, o[fe], 0, 0, 0);
            }
    }

    // final cross-lane row-sum (once)
    float lrow[4];
#pragma unroll
    for (int r = 0; r < 4; ++r) {
        float v = lpart[r];
#pragma unroll
        for (int off = 1; off < 16; off <<= 1) v += __shfl_xor(v, off);
        lrow[r] = v;
    }

    const int b_ = bh >> 4, h_ = bh & 15;
#pragma unroll
    for (int fe = 0; fe < 4; ++fe)
#pragma unroll
        for (int r = 0; r < 4; ++r) {
            const int npos = q0 + wid * 16 + fgrp * 4 + r;
            const size_t idx = ((size_t)(b_ * 2048 + npos)) * 1024 + h_ * 64 + fe * 16 + fr;
            x2[idx] = x[idx] + o[fe][r] / lrow[r];
        }
}

// ---------------- launch ----------------
extern "C" void kernel_launch(void* const* d_in, const int* in_sizes, int n_in,
                              void* d_out, int out_size, void* d_ws, size_t ws_size,
                              hipStream_t stream) {
    const float* x = (const float*)d_in[0];
    const float* wq = (const float*)d_in[1];
    const float* bq = (const float*)d_in[2];
    const float* wk = (const float*)d_in[3];
    const float* bk = (const float*)d_in[4];
    const float* wv = (const float*)d_in[5];
    const float* bv = (const float*)d_in[6];
    const float* g1 = (const float*)d_in[7];
    const float* b1 = (const float*)d_in[8];
    const float* g2 = (const float*)d_in[9];
    const float* b2 = (const float*)d_in[10];
    const float* w1 = (const float*)d_in[11];
    const float* bw1 = (const float*)d_in[12];
    const float* gf = (const float*)d_in[13];
    const float* bf = (const float*)d_in[14];
    const float* w2 = (const float*)d_in[15];
    const float* bw2 = (const float*)d_in[16];
    float* out = (float*)d_out;

    constexpr int Bc = 2, Nc = 2048, Dc = 1024, Fc = 4096, Mc = 4096;

    char* ws = (char*)d_ws;
    auto alloc = [&](size_t bytes) {
        char* p = ws;
        ws += (bytes + 255) & ~(size_t)255;
        return p;
    };
    u16* wqtH = (u16*)alloc((size_t)Dc * Dc * 2);
    u16* wqtL = (u16*)alloc((size_t)Dc * Dc * 2);
    u16* wktH = (u16*)alloc((size_t)Dc * Dc * 2);
    u16* wktL = (u16*)alloc((size_t)Dc * Dc * 2);
    u16* wvt = (u16*)alloc((size_t)Dc * Dc * 2);
    u16* w1t = (u16*)alloc((size_t)Dc * Fc * 2);
    u16* w2t = (u16*)alloc((size_t)Fc * Dc * 2);
    char* region = (char*)alloc((size_t)Mc * Dc * 2 * 7);
    u16* h1H = (u16*)region;
    u16* h1L = h1H + (size_t)Mc * Dc;
    u16* qbH = h1L + (size_t)Mc * Dc;
    u16* qbL = qbH + (size_t)Mc * Dc;
    u16* kbH = qbL + (size_t)Mc * Dc;
    u16* kbL = kbH + (size_t)Mc * Dc;
    u16* vtb = kbL + (size_t)Mc * Dc;
    u16* mid = (u16*)region;  // alias: h1/q dead once attention is done
    float* x2 = (float*)alloc((size_t)Mc * Dc * 4);
    u16* h2 = (u16*)alloc((size_t)Mc * Dc * 2);

    const dim3 tb(32, 8);
    transpose_cast_split<<<dim3(Dc / 32, Dc / 32), tb, 0, stream>>>(wq, wqtH, wqtL, Dc, Dc);
    transpose_cast_split<<<dim3(Dc / 32, Dc / 32), tb, 0, stream>>>(wk, wktH, wktL, Dc, Dc);
    transpose_cast<<<dim3(Dc / 32, Dc / 32), tb, 0, stream>>>(wv, wvt, Dc, Dc);
    transpose_cast<<<dim3(Fc / 32, Dc / 32), tb, 0, stream>>>(w1, w1t, Dc, Fc);
    transpose_cast<<<dim3(Dc / 32, Fc / 32), tb, 0, stream>>>(w2, w2t, Fc, Dc);

    ln_f32_bf16_split<<<Mc, 256, 0, stream>>>(x, g1, b1, h1H, h1L);

    gemm_split_qk<<<dim3(Dc / 64, Mc / 128), 256, 0, stream>>>(h1H, h1L, wqtH, wqtL, bq, qbH, qbL, Mc, Dc, Dc);
    gemm_split_qk<<<dim3(Dc / 64, Mc / 128), 256, 0, stream>>>(h1H, h1L, wktH, wktL, bk, kbH, kbL, Mc, Dc, Dc);
    gemm_bf16<3, 64><<<dim3(Dc / 64, Mc / 128), 256, 0, stream>>>(h1H, wvt, bv, vtb, nullptr, Mc, Dc, Dc);

    attn_kernel<<<Bc * 16 * (Nc / 128), 512, 0, stream>>>(qbH, qbL, kbH, kbL, vtb, x, x2);

    ln_f32_bf16<<<Mc, 256, 0, stream>>>(x2, g2, b2, h2);

    gemm_bf16<0, 128><<<dim3(Fc / 128, Mc / 128), 256, 0, stream>>>(h2, w1t, bw1, mid, nullptr, Mc, Fc, Dc);

    ln_relu_bf16<<<Mc, 256, 0, stream>>>(mid, gf, bf);

    gemm_bf16<1, 64><<<dim3(Dc / 64, Mc / 128), 256, 0, stream>>>(mid, w2t, bw2, nullptr, out, Mc, Dc, Fc);
}

// Round 5
// 354.403 us; speedup vs baseline: 1.2377x; 1.0580x over previous
//
#include <hip/hip_runtime.h>

typedef unsigned short u16;
typedef short bf16x8 __attribute__((ext_vector_type(8)));
typedef float f32x4 __attribute__((ext_vector_type(4)));
typedef unsigned short u16x4 __attribute__((ext_vector_type(4)));
typedef unsigned int u32x4 __attribute__((ext_vector_type(4)));

__device__ __forceinline__ u16 f2b(float f) {
    unsigned u = __float_as_uint(f);
    u += 0x7fffu + ((u >> 16) & 1u);
    return (u16)(u >> 16);
}
__device__ __forceinline__ float b2f(u16 h) { return __uint_as_float((unsigned)h << 16); }

// pack two f32 -> two bf16 in one u32 (RNE), single VALU op
__device__ __forceinline__ unsigned cvtpk(float lo, float hi) {
    unsigned r;
    asm volatile("v_cvt_pk_bf16_f32 %0, %1, %2" : "=v"(r) : "v"(lo), "v"(hi));
    return r;
}

// async global -> LDS, 16B per lane; LDS dest is wave-uniform base + lane*16
__device__ __forceinline__ void gload16(const u16* g, u16* l) {
    __builtin_amdgcn_global_load_lds((const __attribute__((address_space(1))) unsigned int*)g,
                                     (__attribute__((address_space(3))) unsigned int*)l, 16, 0, 0);
}

// ---------------- transpose + cast fp32 -> bf16, Wt[n][k] = W[k][n] ----------------
__global__ void transpose_cast(const float* __restrict__ W, u16* __restrict__ Wt,
                               int K, int N) {
    __shared__ float t[32][33];
    const int n0 = blockIdx.x * 32, k0 = blockIdx.y * 32;
    const int tx = threadIdx.x, ty = threadIdx.y;
#pragma unroll
    for (int i = 0; i < 32; i += 8)
        t[ty + i][tx] = W[(size_t)(k0 + ty + i) * N + n0 + tx];
    __syncthreads();
#pragma unroll
    for (int i = 0; i < 32; i += 8)
        Wt[(size_t)(n0 + ty + i) * K + k0 + tx] = f2b(t[tx][ty + i]);
}

// ---------------- transpose + split cast fp32 -> bf16 hi/lo (two weights per launch) ----------------
__global__ void transpose_cast_split2(const float* __restrict__ W0, u16* __restrict__ H0,
                                      u16* __restrict__ L0, const float* __restrict__ W1,
                                      u16* __restrict__ H1, u16* __restrict__ L1,
                                      int K, int N) {
    __shared__ float t[32][33];
    const float* W = blockIdx.z ? W1 : W0;
    u16* WtH = blockIdx.z ? H1 : H0;
    u16* WtL = blockIdx.z ? L1 : L0;
    const int n0 = blockIdx.x * 32, k0 = blockIdx.y * 32;
    const int tx = threadIdx.x, ty = threadIdx.y;
#pragma unroll
    for (int i = 0; i < 32; i += 8)
        t[ty + i][tx] = W[(size_t)(k0 + ty + i) * N + n0 + tx];
    __syncthreads();
#pragma unroll
    for (int i = 0; i < 32; i += 8) {
        const float v = t[tx][ty + i];
        const u16 hi = f2b(v);
        const size_t idx = (size_t)(n0 + ty + i) * K + k0 + tx;
        WtH[idx] = hi;
        WtL[idx] = f2b(v - b2f(hi));
    }
}

// ---------------- LayerNorm fp32 -> bf16, D=1024, one block per row ----------------
__global__ __launch_bounds__(256) void ln_f32_bf16(const float* __restrict__ in,
                                                   const float* __restrict__ g,
                                                   const float* __restrict__ b,
                                                   u16* __restrict__ out) {
    constexpr int Dl = 1024;
    const int row = blockIdx.x, tid = threadIdx.x;
    const float4 v = *(const float4*)&in[(size_t)row * Dl + tid * 4];
    const float* vp = (const float*)&v;
    float s = v.x + v.y + v.z + v.w;
    float s2 = v.x * v.x + v.y * v.y + v.z * v.z + v.w * v.w;
#pragma unroll
    for (int off = 32; off; off >>= 1) { s += __shfl_xor(s, off); s2 += __shfl_xor(s2, off); }
    __shared__ float red[8];
    const int lane = tid & 63, wid = tid >> 6;
    if (lane == 0) { red[wid] = s; red[4 + wid] = s2; }
    __syncthreads();
    s = red[0] + red[1] + red[2] + red[3];
    s2 = red[4] + red[5] + red[6] + red[7];
    const float mean = s * (1.0f / Dl);
    const float rstd = rsqrtf(s2 * (1.0f / Dl) - mean * mean + 1e-5f);
    u16x4 pk;
#pragma unroll
    for (int i = 0; i < 4; ++i) {
        const int col = tid * 4 + i;
        pk[i] = f2b((vp[i] - mean) * rstd * g[col] + b[col]);
    }
    *(u16x4*)&out[(size_t)row * Dl + tid * 4] = pk;
}

// ---------------- LayerNorm fp32 -> bf16 hi/lo pair ----------------
__global__ __launch_bounds__(256) void ln_f32_bf16_split(const float* __restrict__ in,
                                                         const float* __restrict__ g,
                                                         const float* __restrict__ b,
                                                         u16* __restrict__ outH,
                                                         u16* __restrict__ outL) {
    constexpr int Dl = 1024;
    const int row = blockIdx.x, tid = threadIdx.x;
    const float4 v = *(const float4*)&in[(size_t)row * Dl + tid * 4];
    const float* vp = (const float*)&v;
    float s = v.x + v.y + v.z + v.w;
    float s2 = v.x * v.x + v.y * v.y + v.z * v.z + v.w * v.w;
#pragma unroll
    for (int off = 32; off; off >>= 1) { s += __shfl_xor(s, off); s2 += __shfl_xor(s2, off); }
    __shared__ float red[8];
    const int lane = tid & 63, wid = tid >> 6;
    if (lane == 0) { red[wid] = s; red[4 + wid] = s2; }
    __syncthreads();
    s = red[0] + red[1] + red[2] + red[3];
    s2 = red[4] + red[5] + red[6] + red[7];
    const float mean = s * (1.0f / Dl);
    const float rstd = rsqrtf(s2 * (1.0f / Dl) - mean * mean + 1e-5f);
    u16x4 pkH, pkL;
#pragma unroll
    for (int i = 0; i < 4; ++i) {
        const int col = tid * 4 + i;
        const float y = (vp[i] - mean) * rstd * g[col] + b[col];
        pkH[i] = f2b(y);
        pkL[i] = f2b(y - b2f(pkH[i]));
    }
    *(u16x4*)&outH[(size_t)row * Dl + tid * 4] = pkH;
    *(u16x4*)&outL[(size_t)row * Dl + tid * 4] = pkL;
}

// ---------------- LayerNorm + ReLU in-place on bf16, F=4096 ----------------
__global__ __launch_bounds__(256) void ln_relu_bf16(u16* __restrict__ mid,
                                                    const float* __restrict__ g,
                                                    const float* __restrict__ b) {
    constexpr int Fl = 4096;
    const int row = blockIdx.x, tid = threadIdx.x;
    u16* rp = mid + (size_t)row * Fl;
    float v[16];
    u32x4 raw[2];
#pragma unroll
    for (int c = 0; c < 2; ++c) raw[c] = *(const u32x4*)&rp[tid * 16 + c * 8];
#pragma unroll
    for (int c = 0; c < 2; ++c)
#pragma unroll
        for (int j = 0; j < 4; ++j) {
            const unsigned u = raw[c][j];
            v[c * 8 + j * 2] = __uint_as_float(u << 16);
            v[c * 8 + j * 2 + 1] = __uint_as_float(u & 0xffff0000u);
        }
    float s = 0.f, s2 = 0.f;
#pragma unroll
    for (int i = 0; i < 16; ++i) { s += v[i]; s2 += v[i] * v[i]; }
#pragma unroll
    for (int off = 32; off; off >>= 1) { s += __shfl_xor(s, off); s2 += __shfl_xor(s2, off); }
    __shared__ float red[8];
    const int lane = tid & 63, wid = tid >> 6;
    if (lane == 0) { red[wid] = s; red[4 + wid] = s2; }
    __syncthreads();
    s = red[0] + red[1] + red[2] + red[3];
    s2 = red[4] + red[5] + red[6] + red[7];
    const float mean = s * (1.0f / Fl);
    const float rstd = rsqrtf(s2 * (1.0f / Fl) - mean * mean + 1e-5f);
#pragma unroll
    for (int i = 0; i < 16; ++i) {
        const int col = tid * 16 + i;
        const float y = (v[i] - mean) * rstd * g[col] + b[col];
        rp[col] = f2b(fmaxf(y, 0.f));
    }
}

// ---------------- bf16 MFMA GEMM: C = A(MxK) * Bt(NxK)^T + bias ----------------
// EPI 0: bf16 row-major  1: f32 row-major  3: v -> [b][h][e][n]
template <int EPI, int BN>
__global__ __launch_bounds__(256, 2) void gemm_bf16(const u16* __restrict__ A,
                                                    const u16* __restrict__ Bt,
                                                    const float* __restrict__ bias,
                                                    u16* __restrict__ outB,
                                                    float* __restrict__ outF,
                                                    int M_, int N_, int K_) {
    constexpr int BK = 32;
    constexpr int NJ = BN / 32;  // B fragments per wave
    __shared__ u16 As[128 * BK];
    __shared__ u16 Bs[BN * BK];
    const int tid = threadIdx.x;
    const int lane = tid & 63;
    const int wid = tid >> 6;
    const int m0 = blockIdx.y * 128;
    const int n0 = blockIdx.x * BN;
    const int wr = (wid >> 1) * 64;
    const int wc = (wid & 1) * (BN / 2);
    const int fr = lane & 15;
    const int fg = (lane >> 4) * 8;

    const int srow = wid * 32 + (lane >> 2);
    const int srB = wid * (BN / 4) + (lane >> 2);
    const int scol = (lane & 3) * 8;
    const u16* pa0 = A + (size_t)(m0 + srow) * K_ + scol;
    const u16* pa1 = pa0 + (size_t)16 * K_;
    const u16* pb0 = Bt + (size_t)(n0 + srB) * K_ + scol;
    const u16* pb1 = pb0 + (size_t)16 * K_;
    u16* lA0 = As + wid * 1024;
    u16* lA1 = lA0 + 512;
    u16* lB0 = Bs + wid * (BN / 4) * BK;
    u16* lB1 = lB0 + 512;

    f32x4 acc[4][NJ] = {};

    for (int k0 = 0; k0 < K_; k0 += BK) {
        __syncthreads();
        gload16(pa0, lA0); gload16(pa1, lA1);
        gload16(pb0, lB0);
        if constexpr (BN == 128) gload16(pb1, lB1);
        pa0 += BK; pa1 += BK; pb0 += BK; pb1 += BK;
        __syncthreads();
        bf16x8 aF[4], bF[NJ];
#pragma unroll
        for (int i = 0; i < 4; ++i) aF[i] = *(const bf16x8*)&As[(wr + i * 16 + fr) * BK + fg];
#pragma unroll
        for (int j = 0; j < NJ; ++j) bF[j] = *(const bf16x8*)&Bs[(wc + j * 16 + fr) * BK + fg];
#pragma unroll
        for (int i = 0; i < 4; ++i)
#pragma unroll
            for (int j = 0; j < NJ; ++j)
                acc[i][j] = __builtin_amdgcn_mfma_f32_16x16x32_bf16(aF[i], bF[j], acc[i][j], 0, 0, 0);
    }

    const int g4 = (lane >> 4) * 4;
#pragma unroll
    for (int i = 0; i < 4; ++i) {
#pragma unroll
        for (int j = 0; j < NJ; ++j) {
            const int mb = m0 + wr + i * 16 + g4;
            const int nb = n0 + wc + j * 16 + fr;
            const float bv = bias[nb];
            if constexpr (EPI == 0) {
#pragma unroll
                for (int r = 0; r < 4; ++r)
                    outB[(size_t)(mb + r) * N_ + nb] = f2b(acc[i][j][r] + bv);
            } else if constexpr (EPI == 1) {
#pragma unroll
                for (int r = 0; r < 4; ++r)
                    outF[(size_t)(mb + r) * N_ + nb] = acc[i][j][r] + bv;
            } else {
                const int h = nb >> 6, e = nb & 63;
                const int b_ = mb >> 11, np = mb & 2047;
                u16x4 pk;
#pragma unroll
                for (int r = 0; r < 4; ++r) pk[r] = f2b(acc[i][j][r] + bv);
                *(u16x4*)&outB[((size_t)(b_ * 16 + h) * 64 + e) * 2048 + np] = pk;
            }
        }
    }
}

// ------------- split (double-bf16) GEMM for q/k, BN=64, out [b][h][n][e] hi/lo -------------
__global__ __launch_bounds__(256, 2) void gemm_split_qk(const u16* __restrict__ Ah,
                                                        const u16* __restrict__ Al,
                                                        const u16* __restrict__ Bh,
                                                        const u16* __restrict__ Bl,
                                                        const float* __restrict__ bias,
                                                        u16* __restrict__ outH,
                                                        u16* __restrict__ outL,
                                                        int M_, int N_, int K_) {
    constexpr int BK = 32;
    __shared__ u16 AsH[128 * BK];
    __shared__ u16 AsL[128 * BK];
    __shared__ u16 BsH[64 * BK];
    __shared__ u16 BsL[64 * BK];
    const int tid = threadIdx.x;
    const int lane = tid & 63;
    const int wid = tid >> 6;
    const int m0 = blockIdx.y * 128;
    const int n0 = blockIdx.x * 64;
    const int wr = (wid >> 1) * 64;
    const int wc = (wid & 1) * 32;
    const int fr = lane & 15;
    const int fg = (lane >> 4) * 8;

    const int srow = wid * 32 + (lane >> 2);
    const int srB = wid * 16 + (lane >> 2);
    const int scol = (lane & 3) * 8;
    const size_t oa = (size_t)(m0 + srow) * K_ + scol;
    const size_t ob = (size_t)(n0 + srB) * K_ + scol;
    const u16* pah0 = Ah + oa; const u16* pah1 = pah0 + (size_t)16 * K_;
    const u16* pal0 = Al + oa; const u16* pal1 = pal0 + (size_t)16 * K_;
    const u16* pbh = Bh + ob;
    const u16* pbl = Bl + ob;
    u16* lah0 = AsH + wid * 1024; u16* lah1 = lah0 + 512;
    u16* lal0 = AsL + wid * 1024; u16* lal1 = lal0 + 512;
    u16* lbh = BsH + wid * 512;
    u16* lbl = BsL + wid * 512;

    f32x4 acc[4][2] = {};

    for (int k0 = 0; k0 < K_; k0 += BK) {
        __syncthreads();
        gload16(pah0, lah0); gload16(pah1, lah1);
        gload16(pal0, lal0); gload16(pal1, lal1);
        gload16(pbh, lbh);   gload16(pbl, lbl);
        pah0 += BK; pah1 += BK; pal0 += BK; pal1 += BK;
        pbh += BK; pbl += BK;
        __syncthreads();
        bf16x8 aH[4], aL[4], bH[2], bL[2];
#pragma unroll
        for (int i = 0; i < 4; ++i) {
            aH[i] = *(const bf16x8*)&AsH[(wr + i * 16 + fr) * BK + fg];
            aL[i] = *(const bf16x8*)&AsL[(wr + i * 16 + fr) * BK + fg];
        }
#pragma unroll
        for (int j = 0; j < 2; ++j) {
            bH[j] = *(const bf16x8*)&BsH[(wc + j * 16 + fr) * BK + fg];
            bL[j] = *(const bf16x8*)&BsL[(wc + j * 16 + fr) * BK + fg];
        }
#pragma unroll
        for (int i = 0; i < 4; ++i)
#pragma unroll
            for (int j = 0; j < 2; ++j) {
                acc[i][j] = __builtin_amdgcn_mfma_f32_16x16x32_bf16(aH[i], bH[j], acc[i][j], 0, 0, 0);
                acc[i][j] = __builtin_amdgcn_mfma_f32_16x16x32_bf16(aH[i], bL[j], acc[i][j], 0, 0, 0);
                acc[i][j] = __builtin_amdgcn_mfma_f32_16x16x32_bf16(aL[i], bH[j], acc[i][j], 0, 0, 0);
            }
    }

    const int g4 = (lane >> 4) * 4;
#pragma unroll
    for (int i = 0; i < 4; ++i) {
#pragma unroll
        for (int j = 0; j < 2; ++j) {
            const int mb = m0 + wr + i * 16 + g4;
            const int nb = n0 + wc + j * 16 + fr;
            const float bv = bias[nb];
            const int h = nb >> 6, e = nb & 63;
#pragma unroll
            for (int r = 0; r < 4; ++r) {
                const int m = mb + r;
                const size_t idx = ((size_t)((m >> 11) * 16 + h) * 2048 + (m & 2047)) * 64 + e;
                const float v = acc[i][j][r] + bv;
                const u16 hi = f2b(v);
                outH[idx] = hi;
                outL[idx] = f2b(v - b2f(hi));
            }
        }
    }
}

// ---------------- flash attention + residual: x2 = x + softmax(q k^T * 32) v ----------------
// Swapped QK^T (S^T = mfma(K,Q)) -> per-lane softmax state; cvt_pk P-pack, b64 P writes.
// 512 threads / 128 q-rows per block; KVBLK=64 double-buffered via global_load_lds, vmcnt(3).
__global__ __launch_bounds__(512, 4) void attn_kernel(const u16* __restrict__ qH,
                                                      const u16* __restrict__ qL,
                                                      const u16* __restrict__ kH,
                                                      const u16* __restrict__ kL,
                                                      const u16* __restrict__ vt,
                                                      const float* __restrict__ x,
                                                      float* __restrict__ x2) {
    constexpr int N = 2048, E = 64, KB = 64, NT = N / KB;
    constexpr float L2E = 1.4426950408889634f;
    __shared__ u16 KsH[2][64 * 64];
    __shared__ u16 KsL[2][64 * 64];
    __shared__ u16 Vs[2][64 * 64];
    __shared__ unsigned Ps[8][16][36];  // u32 view of P[q=16][k=64] bf16, row stride 144B

    const int tid = threadIdx.x;
    const int lane = tid & 63;
    const int wid = tid >> 6;
    const int bh = blockIdx.x >> 4;
    const int q0 = (blockIdx.x & 15) * 128;
    const u16* qhh = qH + (size_t)bh * N * E;
    const u16* qhl = qL + (size_t)bh * N * E;
    const u16* khh = kH + (size_t)bh * N * E;
    const u16* khl = kL + (size_t)bh * N * E;
    const u16* vh = vt + (size_t)bh * E * N;

    const int fr = lane & 15;
    const int fgrp = lane >> 4;
    const int fg8 = fgrp * 8;
    // physical (swizzled) u16 col of the 8-elem fragment at logical col block ks*4+fgrp
    int pc[2];
#pragma unroll
    for (int ks = 0; ks < 2; ++ks) pc[ks] = 8 * (((ks << 2) + fgrp) ^ (fr & 7));

    // staging geometry: wave w stages rows [8w, 8w+8) of KsH/KsL/Vs (1 gload each)
    const int srow = wid * 8 + (lane >> 3);
    const int swc = 8 * ((lane & 7) ^ (lane >> 3));  // pre-swizzled source col
    u16* dKH = &KsH[0][wid * 8 * 64];
    u16* dKL = &KsL[0][wid * 8 * 64];
    u16* dV = &Vs[0][wid * 8 * 64];
    constexpr int BUFO = 64 * 64;

    // q fragments, pre-scaled by 32 (exact in bf16); used as the MFMA B-operand
    bf16x8 qfh[2], qfl[2];
#pragma unroll
    for (int ks = 0; ks < 2; ++ks) {
        const size_t off = (size_t)(q0 + wid * 16 + fr) * E + ks * 32 + fg8;
        bf16x8 th = *(const bf16x8*)&qhh[off];
        bf16x8 tl = *(const bf16x8*)&qhl[off];
#pragma unroll
        for (int e = 0; e < 8; ++e) {
            th[e] = (short)f2b(b2f((u16)th[e]) * 32.f);
            tl[e] = (short)f2b(b2f((u16)tl[e]) * 32.f);
        }
        qfh[ks] = th;
        qfl[ks] = tl;
    }

    auto stage = [&](int t, int buf) {
        const size_t kb = (size_t)t * KB;
        gload16(khh + (kb + srow) * E + swc, dKH + buf * BUFO);
        gload16(khl + (kb + srow) * E + swc, dKL + buf * BUFO);
        gload16(vh + (size_t)srow * N + kb + swc, dV + buf * BUFO);
    };

    f32x4 o[4] = {};
    float mrow = -1e30f, lpart = 0.f;  // per-lane state for q-row (wid*16 + fr)

    stage(0, 0);

    for (int t = 0; t < NT; ++t) {
        const int buf = t & 1;
        __syncthreads();  // all reads of buf^1 (prev tile) done -> safe to overwrite
        if (t + 1 < NT) {
            stage(t + 1, buf ^ 1);
            asm volatile("s_waitcnt vmcnt(3)" ::: "memory");  // tile t landed; t+1 in flight
        } else {
            asm volatile("s_waitcnt vmcnt(0)" ::: "memory");
        }
        __syncthreads();  // tile t visible to all waves

        const u16* KH = &KsH[buf][0];
        const u16* KL = &KsL[buf][0];
        const u16* VV = &Vs[buf][0];

        // S^T = K . Q^T : lane holds q-row = wid*16+fr, k = fn*16 + fgrp*4 + r
        f32x4 s[4] = {};
#pragma unroll
        for (int fn = 0; fn < 4; ++fn)
#pragma unroll
            for (int ks = 0; ks < 2; ++ks) {
                const int R = fn * 16 + fr;
                const bf16x8 kfh = *(const bf16x8*)&KH[R * 64 + pc[ks]];
                const bf16x8 kfl = *(const bf16x8*)&KL[R * 64 + pc[ks]];
                s[fn] = __builtin_amdgcn_mfma_f32_16x16x32_bf16(kfh, qfh[ks], s[fn], 0, 0, 0);
                s[fn] = __builtin_amdgcn_mfma_f32_16x16x32_bf16(kfl, qfh[ks], s[fn], 0, 0, 0);
                s[fn] = __builtin_amdgcn_mfma_f32_16x16x32_bf16(kfh, qfl[ks], s[fn], 0, 0, 0);
            }

        // lane-local max over this lane's 16 k's
        float lmax = fmaxf(fmaxf(fmaxf(s[0][0], s[0][1]), fmaxf(s[0][2], s[0][3])),
                           fmaxf(fmaxf(s[1][0], s[1][1]), fmaxf(s[1][2], s[1][3])));
        lmax = fmaxf(lmax, fmaxf(fmaxf(fmaxf(s[2][0], s[2][1]), fmaxf(s[2][2], s[2][3])),
                                 fmaxf(fmaxf(s[3][0], s[3][1]), fmaxf(s[3][2], s[3][3]))));
        if (!__all(lmax <= mrow + 8.f)) {
            float m2 = fmaxf(lmax, __shfl_xor(lmax, 16));
            m2 = fmaxf(m2, __shfl_xor(m2, 32));
            const float mnew = fmaxf(mrow, m2);
            const float fac = exp2f((mrow - mnew) * L2E);
            mrow = mnew;
            lpart *= fac;
            // o rows are q-local fgrp*4+r -> fetch their fac from lanes [0,16)
            float fo[4];
#pragma unroll
            for (int r = 0; r < 4; ++r) fo[r] = __shfl(fac, fgrp * 4 + r);
#pragma unroll
            for (int fe = 0; fe < 4; ++fe)
#pragma unroll
                for (int r = 0; r < 4; ++r) o[fe][r] *= fo[r];
        }

        const float nml = -mrow * L2E;
#pragma unroll
        for (int fn = 0; fn < 4; ++fn) {
            const float p0 = exp2f(fmaf(s[fn][0], L2E, nml));
            const float p1 = exp2f(fmaf(s[fn][1], L2E, nml));
            const float p2 = exp2f(fmaf(s[fn][2], L2E, nml));
            const float p3 = exp2f(fmaf(s[fn][3], L2E, nml));
            lpart += (p0 + p1) + (p2 + p3);
            uint2 w;
            w.x = cvtpk(p0, p1);
            w.y = cvtpk(p2, p3);
            *(uint2*)&Ps[wid][fr][fn * 8 + fgrp * 2] = w;  // k = fn*16+fgrp*4 .. +3
        }

        // PV: P rows (q) are exactly the A-fragment rows
        const u16* prow = (const u16*)&Ps[wid][fr][0];
        bf16x8 pf[2];
#pragma unroll
        for (int ks = 0; ks < 2; ++ks) pf[ks] = *(const bf16x8*)&prow[ks * 32 + fg8];
#pragma unroll
        for (int fe = 0; fe < 4; ++fe)
#pragma unroll
            for (int ks = 0; ks < 2; ++ks) {
                const bf16x8 vf = *(const bf16x8*)&VV[(fe * 16 + fr) * 64 + pc[ks]];
                o[fe] = __builtin_amdgcn_mfma_f32_16x16x32_bf16(pf[ks], vf, o[fe], 0, 0, 0);
            }
    }

    // final row-sum: reduce across the 4 replicas, then fetch per-o-row values
    float lsum = lpart + __shfl_xor(lpart, 16);
    lsum += __shfl_xor(lsum, 32);
    float rl[4];
#pragma unroll
    for (int r = 0; r < 4; ++r) rl[r] = 1.0f / __shfl(lsum, fgrp * 4 + r);

    const int b_ = bh >> 4, h_ = bh & 15;
#pragma unroll
    for (int fe = 0; fe < 4; ++fe)
#pragma unroll
        for (int r = 0; r < 4; ++r) {
            const int npos = q0 + wid * 16 + fgrp * 4 + r;
            const size_t idx = ((size_t)(b_ * 2048 + npos)) * 1024 + h_ * 64 + fe * 16 + fr;
            x2[idx] = x[idx] + o[fe][r] * rl[r];
        }
}

// ---------------- launch ----------------
extern "C" void kernel_launch(void* const* d_in, const int* in_sizes, int n_in,
                              void* d_out, int out_size, void* d_ws, size_t ws_size,
                              hipStream_t stream) {
    const float* x = (const float*)d_in[0];
    const float* wq = (const float*)d_in[1];
    const float* bq = (const float*)d_in[2];
    const float* wk = (const float*)d_in[3];
    const float* bk = (const float*)d_in[4];
    const float* wv = (const float*)d_in[5];
    const float* bv = (const float*)d_in[6];
    const float* g1 = (const float*)d_in[7];
    const float* b1 = (const float*)d_in[8];
    const float* g2 = (const float*)d_in[9];
    const float* b2 = (const float*)d_in[10];
    const float* w1 = (const float*)d_in[11];
    const float* bw1 = (const float*)d_in[12];
    const float* gf = (const float*)d_in[13];
    const float* bf = (const float*)d_in[14];
    const float* w2 = (const float*)d_in[15];
    const float* bw2 = (const float*)d_in[16];
    float* out = (float*)d_out;

    constexpr int Bc = 2, Nc = 2048, Dc = 1024, Fc = 4096, Mc = 4096;

    char* ws = (char*)d_ws;
    auto alloc = [&](size_t bytes) {
        char* p = ws;
        ws += (bytes + 255) & ~(size_t)255;
        return p;
    };
    u16* wqtH = (u16*)alloc((size_t)Dc * Dc * 2);
    u16* wqtL = (u16*)alloc((size_t)Dc * Dc * 2);
    u16* wktH = (u16*)alloc((size_t)Dc * Dc * 2);
    u16* wktL = (u16*)alloc((size_t)Dc * Dc * 2);
    u16* wvt = (u16*)alloc((size_t)Dc * Dc * 2);
    u16* w1t = (u16*)alloc((size_t)Dc * Fc * 2);
    u16* w2t = (u16*)alloc((size_t)Fc * Dc * 2);
    char* region = (char*)alloc((size_t)Mc * Dc * 2 * 7);
    u16* h1H = (u16*)region;
    u16* h1L = h1H + (size_t)Mc * Dc;
    u16* qbH = h1L + (size_t)Mc * Dc;
    u16* qbL = qbH + (size_t)Mc * Dc;
    u16* kbH = qbL + (size_t)Mc * Dc;
    u16* kbL = kbH + (size_t)Mc * Dc;
    u16* vtb = kbL + (size_t)Mc * Dc;
    u16* mid = (u16*)region;  // alias: h1/q dead once attention is done
    float* x2 = (float*)alloc((size_t)Mc * Dc * 4);
    u16* h2 = (u16*)alloc((size_t)Mc * Dc * 2);

    const dim3 tb(32, 8);
    transpose_cast_split2<<<dim3(Dc / 32, Dc / 32, 2), tb, 0, stream>>>(
        wq, wqtH, wqtL, wk, wktH, wktL, Dc, Dc);
    transpose_cast<<<dim3(Dc / 32, Dc / 32), tb, 0, stream>>>(wv, wvt, Dc, Dc);
    transpose_cast<<<dim3(Fc / 32, Dc / 32), tb, 0, stream>>>(w1, w1t, Dc, Fc);
    transpose_cast<<<dim3(Dc / 32, Fc / 32), tb, 0, stream>>>(w2, w2t, Fc, Dc);

    ln_f32_bf16_split<<<Mc, 256, 0, stream>>>(x, g1, b1, h1H, h1L);

    gemm_split_qk<<<dim3(Dc / 64, Mc / 128), 256, 0, stream>>>(h1H, h1L, wqtH, wqtL, bq, qbH, qbL, Mc, Dc, Dc);
    gemm_split_qk<<<dim3(Dc / 64, Mc / 128), 256, 0, stream>>>(h1H, h1L, wktH, wktL, bk, kbH, kbL, Mc, Dc, Dc);
    gemm_bf16<3, 64><<<dim3(Dc / 64, Mc / 128), 256, 0, stream>>>(h1H, wvt, bv, vtb, nullptr, Mc, Dc, Dc);

    attn_kernel<<<Bc * 16 * (Nc / 128), 512, 0, stream>>>(qbH, qbL, kbH, kbL, vtb, x, x2);

    ln_f32_bf16<<<Mc, 256, 0, stream>>>(x2, g2, b2, h2);

    gemm_bf16<0, 128><<<dim3(Fc / 128, Mc / 128), 256, 0, stream>>>(h2, w1t, bw1, mid, nullptr, Mc, Fc, Dc);

    ln_relu_bf16<<<Mc, 256, 0, stream>>>(mid, gf, bf);

    gemm_bf16<1, 64><<<dim3(Dc / 64, Mc / 128), 256, 0, stream>>>(mid, w2t, bw2, nullptr, out, Mc, Dc, Fc);
}